// Round 4
// baseline (111.922 us; speedup 1.0000x reference)
//
#include <hip/hip_runtime.h>
#include <math.h>

#define Bn 8
#define NN 200
#define Cc 256
#define RR (Bn*NN)       // 1600 rows total
#define JP 200           // j-stride of transposed nf
#define CW 32            // c-chunk for NT GEMM staging
#define N_EPS 1e-12f
#define LN_EPS 1e-5f
#define SLOPE 0.01f
#define SCALE 5.0f

// ---------------- reduction helpers (blockDim.x == 256) ----------------
__device__ __forceinline__ float wave_reduce_sum(float v) {
    #pragma unroll
    for (int o = 32; o > 0; o >>= 1) v += __shfl_xor(v, o);
    return v;
}

// packed two-value block reductions (sh must hold 8 floats)
__device__ __forceinline__ float2 block_reduce_sum2(float2 v, float* sh) {
    __syncthreads();
    #pragma unroll
    for (int o = 32; o > 0; o >>= 1) { v.x += __shfl_xor(v.x, o); v.y += __shfl_xor(v.y, o); }
    if ((threadIdx.x & 63) == 0) { int w = threadIdx.x >> 6; sh[w*2] = v.x; sh[w*2+1] = v.y; }
    __syncthreads();
    return make_float2(sh[0]+sh[2]+sh[4]+sh[6], sh[1]+sh[3]+sh[5]+sh[7]);
}

__device__ __forceinline__ float2 block_reduce_max2(float2 v, float* sh) {
    __syncthreads();
    #pragma unroll
    for (int o = 32; o > 0; o >>= 1) {
        v.x = fmaxf(v.x, __shfl_xor(v.x, o));
        v.y = fmaxf(v.y, __shfl_xor(v.y, o));
    }
    if ((threadIdx.x & 63) == 0) { int w = threadIdx.x >> 6; sh[w*2] = v.x; sh[w*2+1] = v.y; }
    __syncthreads();
    return make_float2(fmaxf(fmaxf(sh[0], sh[2]), fmaxf(sh[4], sh[6])),
                       fmaxf(fmaxf(sh[1], sh[3]), fmaxf(sh[5], sh[7])));
}

// ---------------- GEMM building blocks (smem passed in, shared between branches) ----------------
// smem layout: sx = smem[0 .. 4*Cc), sw = smem[4*Cc .. 4*Cc + CW*(Cc+1))
#define SMEM_FLOATS (4*Cc + CW*(Cc+1))

// l2-normalize 4 rows of X, write transposed into nfT[b][c][j], Y = nf@W (NN layout).
__device__ __forceinline__ void gemm4_normT(int blk, const float* __restrict__ X,
        const float* __restrict__ W, float* __restrict__ nfT, float* __restrict__ Y,
        float* smem) {
    float (*sx)[Cc] = (float(*)[Cc])smem;
    int t = threadIdx.x, lane = t & 63, wv = t >> 6;
    int r0 = blk * 4;
    float4 x = ((const float4*)(X + (size_t)(r0 + wv) * Cc))[lane];
    float ss = wave_reduce_sum(x.x*x.x + x.y*x.y + x.z*x.z + x.w*x.w);
    float inv = 1.f / fmaxf(sqrtf(ss), N_EPS);
    x.x *= inv; x.y *= inv; x.z *= inv; x.w *= inv;
    ((float4*)&sx[wv][0])[lane] = x;
    __syncthreads();
    int b = r0 / NN, i0 = r0 % NN;
    float4 col;
    col.x = sx[0][t]; col.y = sx[1][t]; col.z = sx[2][t]; col.w = sx[3][t];
    *((float4*)(nfT + (size_t)b * Cc * JP + (size_t)t * JP + i0)) = col;
    float a0 = 0.f, a1 = 0.f, a2 = 0.f, a3 = 0.f;
    #pragma unroll 8
    for (int c = 0; c < Cc; c++) {
        float w = W[(size_t)c * Cc + t];
        a0 = fmaf(sx[0][c], w, a0);
        a1 = fmaf(sx[1][c], w, a1);
        a2 = fmaf(sx[2][c], w, a2);
        a3 = fmaf(sx[3][c], w, a3);
    }
    Y[(size_t)(r0+0)*Cc + t] = a0;
    Y[(size_t)(r0+1)*Cc + t] = a1;
    Y[(size_t)(r0+2)*Cc + t] = a2;
    Y[(size_t)(r0+3)*Cc + t] = a3;
}

// NT GEMM: Y[r,d] = sum_c X[r,c]*W[d,c] (+bias[d]).  W staged transposed via LDS.
__device__ __forceinline__ void gemm4_nt(int blk, const float* __restrict__ X,
        const float* __restrict__ W, const float* __restrict__ bias, float* __restrict__ Y,
        float* smem) {
    float (*sx)[Cc] = (float(*)[Cc])smem;
    float (*sw)[Cc + 1] = (float(*)[Cc + 1])(smem + 4 * Cc);   // [CW][Cc+1] indexed [c][d]
    int t = threadIdx.x, lane = t & 63, wv = t >> 6;
    int r0 = blk * 4;
    float4 x = ((const float4*)(X + (size_t)(r0 + wv) * Cc))[lane];
    ((float4*)&sx[wv][0])[lane] = x;
    float a0 = 0.f, a1 = 0.f, a2 = 0.f, a3 = 0.f;
    for (int cc = 0; cc < Cc; cc += CW) {
        __syncthreads();           // also covers initial sx fill
        #pragma unroll 8
        for (int it = 0; it < CW; it++) {       // 8192 elems = 256 d x 32 c
            int idx = it * 256 + t;
            int d = idx >> 5;
            int c = idx & 31;
            sw[c][d] = W[(size_t)d * Cc + cc + c];
        }
        __syncthreads();
        #pragma unroll
        for (int c = 0; c < CW; c++) {
            float w = sw[c][t];
            a0 = fmaf(sx[0][cc + c], w, a0);
            a1 = fmaf(sx[1][cc + c], w, a1);
            a2 = fmaf(sx[2][cc + c], w, a2);
            a3 = fmaf(sx[3][cc + c], w, a3);
        }
    }
    if (bias) { float bv = bias[t]; a0 += bv; a1 += bv; a2 += bv; a3 += bv; }
    Y[(size_t)(r0+0)*Cc + t] = a0;
    Y[(size_t)(r0+1)*Cc + t] = a1;
    Y[(size_t)(r0+2)*Cc + t] = a2;
    Y[(size_t)(r0+3)*Cc + t] = a3;
}

// ---------------- dispatch 1: nfT + M + P (no transposes needed) ----------------
__global__ void k_pre(const float* __restrict__ lf, const float* __restrict__ dp_adj_w,
                      const float* __restrict__ dp_aff_w,
                      float* __restrict__ nfT, float* __restrict__ M, float* __restrict__ P) {
    __shared__ float smem[SMEM_FLOATS];
    int bid = blockIdx.x;
    if (bid < RR/4) gemm4_normT(bid, lf, dp_adj_w, nfT, M, smem);
    else            gemm4_nt(bid - RR/4, lf, dp_aff_w, nullptr, P, smem);
}

// ---------------- dispatch 2: diff_prop row kernel (2 rows/block) ----------------
__global__ void k_row1(const float* __restrict__ nfT, const float* __restrict__ M,
                       const float* __restrict__ P, const float* __restrict__ bias,
                       const float* __restrict__ g, const float* __restrict__ bb,
                       float* __restrict__ x1) {
    __shared__ float sm0[Cc], sm1[Cc];
    __shared__ float sa0[NN], sa1[NN];
    __shared__ float sh[8];
    int t = threadIdx.x;
    int b = blockIdx.x / (NN/2);
    int i0 = (blockIdx.x % (NN/2)) * 2;
    size_t base = (size_t)b * NN * Cc;
    sm0[t] = M[base + (size_t)i0 * Cc + t];
    sm1[t] = M[base + (size_t)(i0+1) * Cc + t];
    __syncthreads();
    // phase A: A[i0,j], A[i0+1,j] for j=t (serial c-reduction, coalesced nfT loads)
    if (t < NN) {
        const float* nfc = nfT + (size_t)b * Cc * JP + t;
        float a0 = 0.f, a1 = 0.f;
        #pragma unroll 8
        for (int c = 0; c < Cc; c++) {
            float q = nfc[(size_t)c * JP];
            a0 = fmaf(sm0[c], q, a0);
            a1 = fmaf(sm1[c], q, a1);
        }
        sa0[t] = a0; sa1[t] = a1;
    }
    // phase B (packed): exp(5*(a-max)), zero diag, L1 norm, row-sum s
    float2 vm;
    vm.x = (t < NN) ? sa0[t] : -INFINITY;   // NOTE: sa written by this thread or -inf; need sync
    vm.y = (t < NN) ? sa1[t] : -INFINITY;
    // block_reduce_max2 starts with __syncthreads(), but vm reads sa0[t] written by t itself — safe.
    float2 m = block_reduce_max2(vm, sh);
    float e0 = (t < NN && t != i0)     ? expf(SCALE * (vm.x - m.x)) : 0.f;
    float e1 = (t < NN && t != i0 + 1) ? expf(SCALE * (vm.y - m.y)) : 0.f;
    float2 sum = block_reduce_sum2(make_float2(e0, e1), sh);
    float A0 = e0 / fmaxf(sum.x, N_EPS);
    float A1 = e1 / fmaxf(sum.y, N_EPS);
    if (t < NN) { sa0[t] = A0; sa1[t] = A1; }
    float2 s2 = block_reduce_sum2(make_float2(A0, A1), sh);  // leading sync protects sa stores
    float s0 = s2.x, s1 = s2.y;
    // phase C: y = s*(P_i + bias) - sum_j a_j P_j
    const float* Pb = P + base;
    float acc0 = 0.f, acc1 = 0.f;
    #pragma unroll 8
    for (int j = 0; j < NN; j++) {
        float pv = Pb[(size_t)j * Cc + t];
        acc0 = fmaf(sa0[j], pv, acc0);
        acc1 = fmaf(sa1[j], pv, acc1);
    }
    float bv = bias[t];
    float y0 = fmaf(s0, Pb[(size_t)i0 * Cc + t] + bv, -acc0);
    float y1 = fmaf(s1, Pb[(size_t)(i0+1) * Cc + t] + bv, -acc1);
    // phase E (packed): LayerNorm + LeakyReLU
    float gg = g[t], bbv = bb[t];
    float2 mean2 = block_reduce_sum2(make_float2(y0, y1), sh);
    float d0 = y0 - mean2.x * (1.f/256.f);
    float d1 = y1 - mean2.y * (1.f/256.f);
    float2 var2 = block_reduce_sum2(make_float2(d0*d0, d1*d1), sh);
    float z0 = d0 / sqrtf(var2.x * (1.f/256.f) + LN_EPS) * gg + bbv;
    float z1 = d1 / sqrtf(var2.y * (1.f/256.f) + LN_EPS) * gg + bbv;
    x1[base + (size_t)i0 * Cc + t]     = (z0 >= 0.f) ? z0 : SLOPE * z0;
    x1[base + (size_t)(i0+1) * Cc + t] = (z1 >= 0.f) ? z1 : SLOPE * z1;
}

// ---------------- dispatch 3: nf2T/M2 + lf2 ----------------
__global__ void k_mid(const float* __restrict__ x1, const float* __restrict__ fa_adj_w,
                      const float* __restrict__ fa_aff_w, const float* __restrict__ fa_aff_b,
                      float* __restrict__ nfT, float* __restrict__ M, float* __restrict__ lf2) {
    __shared__ float smem[SMEM_FLOATS];
    int bid = blockIdx.x;
    if (bid < RR/4) gemm4_normT(bid, x1, fa_adj_w, nfT, M, smem);
    else            gemm4_nt(bid - RR/4, x1, fa_aff_w, fa_aff_b, lf2, smem);
}

// ---------------- dispatch 4: feat_aggr row kernel (+ nf3 epilogue) ----------------
__global__ void k_row2(const float* __restrict__ nfT, const float* __restrict__ M,
                       const float* __restrict__ lf2, const float* __restrict__ g,
                       const float* __restrict__ bb, float* __restrict__ x2,
                       float* __restrict__ nf3) {
    __shared__ float sm0[Cc], sm1[Cc];
    __shared__ float sa0[NN], sa1[NN];
    __shared__ float sh[8];
    int t = threadIdx.x;
    int b = blockIdx.x / (NN/2);
    int i0 = (blockIdx.x % (NN/2)) * 2;
    size_t base = (size_t)b * NN * Cc;
    sm0[t] = M[base + (size_t)i0 * Cc + t];
    sm1[t] = M[base + (size_t)(i0+1) * Cc + t];
    __syncthreads();
    if (t < NN) {
        const float* nfc = nfT + (size_t)b * Cc * JP + t;
        float a0 = 0.f, a1 = 0.f;
        #pragma unroll 8
        for (int c = 0; c < Cc; c++) {
            float q = nfc[(size_t)c * JP];
            a0 = fmaf(sm0[c], q, a0);
            a1 = fmaf(sm1[c], q, a1);
        }
        sa0[t] = a0; sa1[t] = a1;
    }
    // softmax rows (packed)
    float2 vm;
    vm.x = (t < NN) ? sa0[t] : -INFINITY;
    vm.y = (t < NN) ? sa1[t] : -INFINITY;
    float2 m = block_reduce_max2(vm, sh);
    float e0 = (t < NN) ? expf(SCALE * (vm.x - m.x)) : 0.f;
    float e1 = (t < NN) ? expf(SCALE * (vm.y - m.y)) : 0.f;
    float2 sum = block_reduce_sum2(make_float2(e0, e1), sh);
    if (t < NN) { sa0[t] = e0 / sum.x; sa1[t] = e1 / sum.y; }
    __syncthreads();
    // y = A @ lf2
    const float* l2b = lf2 + base;
    float y0 = 0.f, y1 = 0.f;
    #pragma unroll 8
    for (int j = 0; j < NN; j++) {
        float xv = l2b[(size_t)j * Cc + t];
        y0 = fmaf(sa0[j], xv, y0);
        y1 = fmaf(sa1[j], xv, y1);
    }
    // LN + leaky + l2norm epilogue (packed)
    float gg = g[t], bbv = bb[t];
    float2 mean2 = block_reduce_sum2(make_float2(y0, y1), sh);
    float d0 = y0 - mean2.x * (1.f/256.f);
    float d1 = y1 - mean2.y * (1.f/256.f);
    float2 var2 = block_reduce_sum2(make_float2(d0*d0, d1*d1), sh);
    float z0 = d0 / sqrtf(var2.x * (1.f/256.f) + LN_EPS) * gg + bbv;
    float z1 = d1 / sqrtf(var2.y * (1.f/256.f) + LN_EPS) * gg + bbv;
    z0 = (z0 >= 0.f) ? z0 : SLOPE * z0;
    z1 = (z1 >= 0.f) ? z1 : SLOPE * z1;
    x2[base + (size_t)i0 * Cc + t]     = z0;
    x2[base + (size_t)(i0+1) * Cc + t] = z1;
    float2 ss2 = block_reduce_sum2(make_float2(z0*z0, z1*z1), sh);
    nf3[base + (size_t)i0 * Cc + t]     = z0 / fmaxf(sqrtf(ss2.x), N_EPS);
    nf3[base + (size_t)(i0+1) * Cc + t] = z1 / fmaxf(sqrtf(ss2.y), N_EPS);
}

// ---------------- dispatch 5: fused wsum + node_att (4 rows/block) ----------------
__global__ void k_natt(const float* __restrict__ x2, const float* __restrict__ nf3,
                       const float* __restrict__ pos, const float* __restrict__ w,
                       const float* __restrict__ nb, float* __restrict__ out) {
    __shared__ float svb[4][Cc];
    int t = threadIdx.x, lane = t & 63, wv = t >> 6;
    int b = blockIdx.x / (NN/4);
    int i = (blockIdx.x % (NN/4)) * 4 + wv;
    const float4* slab = (const float4*)(nf3 + (size_t)b * NN * Cc);
    // each wave accumulates a j-quarter of vb = sum_j w[j]*nf3[b,j,:]
    float4 acc = make_float4(0.f, 0.f, 0.f, 0.f);
    for (int j = wv * 50; j < wv * 50 + 50; j++) {
        float4 q = slab[j * 64 + lane];
        float wj = w[j];
        acc.x = fmaf(wj, q.x, acc.x);
        acc.y = fmaf(wj, q.y, acc.y);
        acc.z = fmaf(wj, q.z, acc.z);
        acc.w = fmaf(wj, q.w, acc.w);
    }
    ((float4*)&svb[wv][0])[lane] = acc;
    __syncthreads();
    float4 p0 = ((const float4*)&svb[0][0])[lane];
    float4 p1 = ((const float4*)&svb[1][0])[lane];
    float4 p2 = ((const float4*)&svb[2][0])[lane];
    float4 p3 = ((const float4*)&svb[3][0])[lane];
    float4 vb;
    vb.x = (p0.x + p1.x) + (p2.x + p3.x);
    vb.y = (p0.y + p1.y) + (p2.y + p3.y);
    vb.z = (p0.z + p1.z) + (p2.z + p3.z);
    vb.w = (p0.w + p1.w) + (p2.w + p3.w);
    size_t bi = (size_t)b * NN + i;
    float4 nv = ((const float4*)(nf3 + bi * Cc))[lane];
    float val = nv.x*vb.x + nv.y*vb.y + nv.z*vb.z + nv.w*vb.w;
    if (lane < 9) val += pos[bi * 9 + lane] * w[NN + lane];
    val = wave_reduce_sum(val);
    float att = 1.f / (1.f + expf(-(val + nb[0])));
    float4 xo = ((const float4*)(x2 + bi * Cc))[lane];
    xo.x *= att; xo.y *= att; xo.z *= att; xo.w *= att;
    ((float4*)(out + bi * Cc))[lane] = xo;
}

// ---------------- launcher ----------------
extern "C" void kernel_launch(void* const* d_in, const int* in_sizes, int n_in,
                              void* d_out, int out_size, void* d_ws, size_t ws_size,
                              hipStream_t stream) {
    (void)in_sizes; (void)n_in; (void)out_size; (void)ws_size;
    const float* lf       = (const float*)d_in[0];
    const float* pos      = (const float*)d_in[2];
    const float* dp_adj_w = (const float*)d_in[3];
    const float* dp_aff_w = (const float*)d_in[4];
    const float* dp_aff_b = (const float*)d_in[5];
    const float* dp_ln_g  = (const float*)d_in[6];
    const float* dp_ln_b  = (const float*)d_in[7];
    const float* fa_adj_w = (const float*)d_in[8];
    const float* fa_aff_w = (const float*)d_in[9];
    const float* fa_aff_b = (const float*)d_in[10];
    const float* fa_ln_g  = (const float*)d_in[11];
    const float* fa_ln_b  = (const float*)d_in[12];
    const float* na_w     = (const float*)d_in[13];
    const float* na_b     = (const float*)d_in[14];
    float* out = (float*)d_out;
    float* ws  = (float*)d_ws;

    float* nfT = ws;                   // Bn*Cc*JP (reused stage 2)
    float* M   = nfT + Bn * Cc * JP;   // RR*Cc (reused for M2)
    float* P   = M   + RR * Cc;        // RR*Cc (reused for lf2)
    float* x1  = P   + RR * Cc;        // RR*Cc
    float* x2  = x1  + RR * Cc;        // RR*Cc
    float* nf3 = x2  + RR * Cc;        // RR*Cc

    dim3 blk(256);
    k_pre <<<RR/4 * 2, blk, 0, stream>>>(lf, dp_adj_w, dp_aff_w, nfT, M, P);
    k_row1<<<Bn * NN/2, blk, 0, stream>>>(nfT, M, P, dp_aff_b, dp_ln_g, dp_ln_b, x1);
    k_mid <<<RR/4 * 2, blk, 0, stream>>>(x1, fa_adj_w, fa_aff_w, fa_aff_b, nfT, M, P);
    k_row2<<<Bn * NN/2, blk, 0, stream>>>(nfT, M, P, fa_ln_g, fa_ln_b, x2, nf3);
    k_natt<<<Bn * NN/4, blk, 0, stream>>>(x2, nf3, pos, na_w, na_b, out);
}

// Round 5
// 97.522 us; speedup vs baseline: 1.1477x; 1.1477x over previous
//
#include <hip/hip_runtime.h>
#include <math.h>

#define Bn 8
#define NN 200
#define Cc 256
#define RR (Bn*NN)       // 1600 rows total
#define JP 200           // j-stride of transposed nf
#define N_EPS 1e-12f
#define LN_EPS 1e-5f
#define SLOPE 0.01f
#define SCALE 5.0f

// ---------------- reduction helpers (blockDim.x == 256) ----------------
__device__ __forceinline__ float wave_reduce_sum(float v) {
    #pragma unroll
    for (int o = 32; o > 0; o >>= 1) v += __shfl_xor(v, o);
    return v;
}

// packed two-value block reductions (sh must hold 8 floats)
__device__ __forceinline__ float2 block_reduce_sum2(float2 v, float* sh) {
    __syncthreads();
    #pragma unroll
    for (int o = 32; o > 0; o >>= 1) { v.x += __shfl_xor(v.x, o); v.y += __shfl_xor(v.y, o); }
    if ((threadIdx.x & 63) == 0) { int w = threadIdx.x >> 6; sh[w*2] = v.x; sh[w*2+1] = v.y; }
    __syncthreads();
    return make_float2(sh[0]+sh[2]+sh[4]+sh[6], sh[1]+sh[3]+sh[5]+sh[7]);
}

__device__ __forceinline__ float2 block_reduce_max2(float2 v, float* sh) {
    __syncthreads();
    #pragma unroll
    for (int o = 32; o > 0; o >>= 1) {
        v.x = fmaxf(v.x, __shfl_xor(v.x, o));
        v.y = fmaxf(v.y, __shfl_xor(v.y, o));
    }
    if ((threadIdx.x & 63) == 0) { int w = threadIdx.x >> 6; sh[w*2] = v.x; sh[w*2+1] = v.y; }
    __syncthreads();
    return make_float2(fmaxf(fmaxf(sh[0], sh[2]), fmaxf(sh[4], sh[6])),
                       fmaxf(fmaxf(sh[1], sh[3]), fmaxf(sh[5], sh[7])));
}

// ---------------- 4-row GEMM building blocks ----------------
// l2-normalize 4 rows of X, write transposed into nfT[b][c][j], Y = nf@W.
__device__ __forceinline__ void gemm4_normT(int blk, const float* __restrict__ X,
        const float* __restrict__ W, float* __restrict__ nfT, float* __restrict__ Y,
        float* smem) {
    float (*sx)[Cc] = (float(*)[Cc])smem;
    int t = threadIdx.x, lane = t & 63, wv = t >> 6;
    int r0 = blk * 4;
    float4 x = ((const float4*)(X + (size_t)(r0 + wv) * Cc))[lane];
    float ss = wave_reduce_sum(x.x*x.x + x.y*x.y + x.z*x.z + x.w*x.w);
    float inv = 1.f / fmaxf(sqrtf(ss), N_EPS);
    x.x *= inv; x.y *= inv; x.z *= inv; x.w *= inv;
    ((float4*)&sx[wv][0])[lane] = x;
    __syncthreads();
    int b = r0 / NN, i0 = r0 % NN;
    float4 col;
    col.x = sx[0][t]; col.y = sx[1][t]; col.z = sx[2][t]; col.w = sx[3][t];
    *((float4*)(nfT + (size_t)b * Cc * JP + (size_t)t * JP + i0)) = col;
    float a0 = 0.f, a1 = 0.f, a2 = 0.f, a3 = 0.f;
    #pragma unroll 8
    for (int c = 0; c < Cc; c++) {
        float w = W[(size_t)c * Cc + t];
        a0 = fmaf(sx[0][c], w, a0);
        a1 = fmaf(sx[1][c], w, a1);
        a2 = fmaf(sx[2][c], w, a2);
        a3 = fmaf(sx[3][c], w, a3);
    }
    Y[(size_t)(r0+0)*Cc + t] = a0;
    Y[(size_t)(r0+1)*Cc + t] = a1;
    Y[(size_t)(r0+2)*Cc + t] = a2;
    Y[(size_t)(r0+3)*Cc + t] = a3;
}

// plain 4-row GEMM: Y = X@W (+bias)
__device__ __forceinline__ void gemm4_plain(int blk, const float* __restrict__ X,
        const float* __restrict__ W, const float* __restrict__ bias, float* __restrict__ Y,
        float* smem) {
    float (*sx)[Cc] = (float(*)[Cc])smem;
    int t = threadIdx.x, lane = t & 63, wv = t >> 6;
    int r0 = blk * 4;
    float4 x = ((const float4*)(X + (size_t)(r0 + wv) * Cc))[lane];
    ((float4*)&sx[wv][0])[lane] = x;
    __syncthreads();
    float a0 = 0.f, a1 = 0.f, a2 = 0.f, a3 = 0.f;
    #pragma unroll 8
    for (int c = 0; c < Cc; c++) {
        float w = W[(size_t)c * Cc + t];
        a0 = fmaf(sx[0][c], w, a0);
        a1 = fmaf(sx[1][c], w, a1);
        a2 = fmaf(sx[2][c], w, a2);
        a3 = fmaf(sx[3][c], w, a3);
    }
    if (bias) { float bv = bias[t]; a0 += bv; a1 += bv; a2 += bv; a3 += bv; }
    Y[(size_t)(r0+0)*Cc + t] = a0;
    Y[(size_t)(r0+1)*Cc + t] = a1;
    Y[(size_t)(r0+2)*Cc + t] = a2;
    Y[(size_t)(r0+3)*Cc + t] = a3;
}

// ---------------- dispatch 0: transpose both aff weights (128 blocks) ----------------
__global__ void k_tr(const float* __restrict__ dp_aff_w, const float* __restrict__ fa_aff_w,
                     float* __restrict__ WT1, float* __restrict__ WT2) {
    __shared__ float tile[32][33];
    int tb = blockIdx.x;
    const float* S; float* D;
    if (tb < 64) { S = dp_aff_w; D = WT1; } else { S = fa_aff_w; D = WT2; tb -= 64; }
    int bx = tb & 7, by = tb >> 3;
    int tx = threadIdx.x & 31, ty = threadIdx.x >> 5;
    #pragma unroll
    for (int k = 0; k < 32; k += 8)
        tile[ty + k][tx] = S[(size_t)(by*32 + ty + k) * Cc + bx*32 + tx];
    __syncthreads();
    #pragma unroll
    for (int k = 0; k < 32; k += 8)
        D[(size_t)(bx*32 + ty + k) * Cc + by*32 + tx] = tile[tx][ty + k];
}

// ---------------- dispatch 1: nfT + M + P ----------------
__global__ void k_pre(const float* __restrict__ lf, const float* __restrict__ dp_adj_w,
                      const float* __restrict__ WT1,
                      float* __restrict__ nfT, float* __restrict__ M, float* __restrict__ P) {
    __shared__ float smem[4*Cc];
    int bid = blockIdx.x;
    if (bid < RR/4) gemm4_normT(bid, lf, dp_adj_w, nfT, M, smem);
    else            gemm4_plain(bid - RR/4, lf, WT1, nullptr, P, smem);
}

// ---------------- dispatch 2: diff_prop row kernel (2 rows/block) ----------------
__global__ void k_row1(const float* __restrict__ nfT, const float* __restrict__ M,
                       const float* __restrict__ P, const float* __restrict__ bias,
                       const float* __restrict__ g, const float* __restrict__ bb,
                       float* __restrict__ x1) {
    __shared__ float sm0[Cc], sm1[Cc];
    __shared__ float sa0[NN], sa1[NN];
    __shared__ float sh[8];
    int t = threadIdx.x;
    int b = blockIdx.x / (NN/2);
    int i0 = (blockIdx.x % (NN/2)) * 2;
    size_t base = (size_t)b * NN * Cc;
    sm0[t] = M[base + (size_t)i0 * Cc + t];
    sm1[t] = M[base + (size_t)(i0+1) * Cc + t];
    __syncthreads();
    // phase A: A[i0,j], A[i0+1,j] for j=t (serial c-reduction, coalesced nfT loads)
    if (t < NN) {
        const float* nfc = nfT + (size_t)b * Cc * JP + t;
        float a0 = 0.f, a1 = 0.f;
        #pragma unroll 8
        for (int c = 0; c < Cc; c++) {
            float q = nfc[(size_t)c * JP];
            a0 = fmaf(sm0[c], q, a0);
            a1 = fmaf(sm1[c], q, a1);
        }
        sa0[t] = a0; sa1[t] = a1;
    }
    // phase B (packed): exp(5*(a-max)), zero diag, L1 norm; s = sum/max(sum,eps)
    float2 vm;
    vm.x = (t < NN) ? sa0[t] : -INFINITY;
    vm.y = (t < NN) ? sa1[t] : -INFINITY;
    float2 m = block_reduce_max2(vm, sh);
    float e0 = (t < NN && t != i0)     ? expf(SCALE * (vm.x - m.x)) : 0.f;
    float e1 = (t < NN && t != i0 + 1) ? expf(SCALE * (vm.y - m.y)) : 0.f;
    float2 sum = block_reduce_sum2(make_float2(e0, e1), sh);
    float A0 = e0 / fmaxf(sum.x, N_EPS);
    float A1 = e1 / fmaxf(sum.y, N_EPS);
    if (t < NN) { sa0[t] = A0; sa1[t] = A1; }
    float s0 = sum.x / fmaxf(sum.x, N_EPS);   // == sum_j a_ij exactly (L1 of nonneg)
    float s1 = sum.y / fmaxf(sum.y, N_EPS);
    __syncthreads();                           // protect sa stores before phase C reads
    // phase C: y = s*(P_i + bias) - sum_j a_j P_j
    const float* Pb = P + base;
    float acc0 = 0.f, acc1 = 0.f;
    #pragma unroll 8
    for (int j = 0; j < NN; j++) {
        float pv = Pb[(size_t)j * Cc + t];
        acc0 = fmaf(sa0[j], pv, acc0);
        acc1 = fmaf(sa1[j], pv, acc1);
    }
    float bv = bias[t];
    float y0 = fmaf(s0, Pb[(size_t)i0 * Cc + t] + bv, -acc0);
    float y1 = fmaf(s1, Pb[(size_t)(i0+1) * Cc + t] + bv, -acc1);
    // phase E (packed): LayerNorm + LeakyReLU
    float gg = g[t], bbv = bb[t];
    float2 mean2 = block_reduce_sum2(make_float2(y0, y1), sh);
    float d0 = y0 - mean2.x * (1.f/256.f);
    float d1 = y1 - mean2.y * (1.f/256.f);
    float2 var2 = block_reduce_sum2(make_float2(d0*d0, d1*d1), sh);
    float z0 = d0 / sqrtf(var2.x * (1.f/256.f) + LN_EPS) * gg + bbv;
    float z1 = d1 / sqrtf(var2.y * (1.f/256.f) + LN_EPS) * gg + bbv;
    x1[base + (size_t)i0 * Cc + t]     = (z0 >= 0.f) ? z0 : SLOPE * z0;
    x1[base + (size_t)(i0+1) * Cc + t] = (z1 >= 0.f) ? z1 : SLOPE * z1;
}

// ---------------- dispatch 3: nf2T/M2 + lf2 ----------------
__global__ void k_mid(const float* __restrict__ x1, const float* __restrict__ fa_adj_w,
                      const float* __restrict__ WT2, const float* __restrict__ fa_aff_b,
                      float* __restrict__ nfT, float* __restrict__ M, float* __restrict__ lf2) {
    __shared__ float smem[4*Cc];
    int bid = blockIdx.x;
    if (bid < RR/4) gemm4_normT(bid, x1, fa_adj_w, nfT, M, smem);
    else            gemm4_plain(bid - RR/4, x1, WT2, fa_aff_b, lf2, smem);
}

// ---------------- dispatch 4: feat_aggr row kernel (+ nf3 epilogue) ----------------
__global__ void k_row2(const float* __restrict__ nfT, const float* __restrict__ M,
                       const float* __restrict__ lf2, const float* __restrict__ g,
                       const float* __restrict__ bb, float* __restrict__ x2,
                       float* __restrict__ nf3) {
    __shared__ float sm0[Cc], sm1[Cc];
    __shared__ float sa0[NN], sa1[NN];
    __shared__ float sh[8];
    int t = threadIdx.x;
    int b = blockIdx.x / (NN/2);
    int i0 = (blockIdx.x % (NN/2)) * 2;
    size_t base = (size_t)b * NN * Cc;
    sm0[t] = M[base + (size_t)i0 * Cc + t];
    sm1[t] = M[base + (size_t)(i0+1) * Cc + t];
    __syncthreads();
    if (t < NN) {
        const float* nfc = nfT + (size_t)b * Cc * JP + t;
        float a0 = 0.f, a1 = 0.f;
        #pragma unroll 8
        for (int c = 0; c < Cc; c++) {
            float q = nfc[(size_t)c * JP];
            a0 = fmaf(sm0[c], q, a0);
            a1 = fmaf(sm1[c], q, a1);
        }
        sa0[t] = a0; sa1[t] = a1;
    }
    // softmax rows (packed)
    float2 vm;
    vm.x = (t < NN) ? sa0[t] : -INFINITY;
    vm.y = (t < NN) ? sa1[t] : -INFINITY;
    float2 m = block_reduce_max2(vm, sh);
    float e0 = (t < NN) ? expf(SCALE * (vm.x - m.x)) : 0.f;
    float e1 = (t < NN) ? expf(SCALE * (vm.y - m.y)) : 0.f;
    float2 sum = block_reduce_sum2(make_float2(e0, e1), sh);
    if (t < NN) { sa0[t] = e0 / sum.x; sa1[t] = e1 / sum.y; }
    __syncthreads();
    // y = A @ lf2
    const float* l2b = lf2 + base;
    float y0 = 0.f, y1 = 0.f;
    #pragma unroll 8
    for (int j = 0; j < NN; j++) {
        float xv = l2b[(size_t)j * Cc + t];
        y0 = fmaf(sa0[j], xv, y0);
        y1 = fmaf(sa1[j], xv, y1);
    }
    // LN + leaky + l2norm epilogue (packed)
    float gg = g[t], bbv = bb[t];
    float2 mean2 = block_reduce_sum2(make_float2(y0, y1), sh);
    float d0 = y0 - mean2.x * (1.f/256.f);
    float d1 = y1 - mean2.y * (1.f/256.f);
    float2 var2 = block_reduce_sum2(make_float2(d0*d0, d1*d1), sh);
    float z0 = d0 / sqrtf(var2.x * (1.f/256.f) + LN_EPS) * gg + bbv;
    float z1 = d1 / sqrtf(var2.y * (1.f/256.f) + LN_EPS) * gg + bbv;
    z0 = (z0 >= 0.f) ? z0 : SLOPE * z0;
    z1 = (z1 >= 0.f) ? z1 : SLOPE * z1;
    x2[base + (size_t)i0 * Cc + t]     = z0;
    x2[base + (size_t)(i0+1) * Cc + t] = z1;
    float2 ss2 = block_reduce_sum2(make_float2(z0*z0, z1*z1), sh);
    nf3[base + (size_t)i0 * Cc + t]     = z0 / fmaxf(sqrtf(ss2.x), N_EPS);
    nf3[base + (size_t)(i0+1) * Cc + t] = z1 / fmaxf(sqrtf(ss2.y), N_EPS);
}

// ---------------- dispatch 5: fused wsum + node_att (4 rows/block) ----------------
__global__ void k_natt(const float* __restrict__ x2, const float* __restrict__ nf3,
                       const float* __restrict__ pos, const float* __restrict__ w,
                       const float* __restrict__ nb, float* __restrict__ out) {
    __shared__ float svb[4][Cc];
    int t = threadIdx.x, lane = t & 63, wv = t >> 6;
    int b = blockIdx.x / (NN/4);
    int i = (blockIdx.x % (NN/4)) * 4 + wv;
    const float4* slab = (const float4*)(nf3 + (size_t)b * NN * Cc);
    // each wave accumulates a j-quarter of vb = sum_j w[j]*nf3[b,j,:]
    float4 acc = make_float4(0.f, 0.f, 0.f, 0.f);
    for (int j = wv * 50; j < wv * 50 + 50; j++) {
        float4 q = slab[j * 64 + lane];
        float wj = w[j];
        acc.x = fmaf(wj, q.x, acc.x);
        acc.y = fmaf(wj, q.y, acc.y);
        acc.z = fmaf(wj, q.z, acc.z);
        acc.w = fmaf(wj, q.w, acc.w);
    }
    ((float4*)&svb[wv][0])[lane] = acc;
    __syncthreads();
    float4 p0 = ((const float4*)&svb[0][0])[lane];
    float4 p1 = ((const float4*)&svb[1][0])[lane];
    float4 p2 = ((const float4*)&svb[2][0])[lane];
    float4 p3 = ((const float4*)&svb[3][0])[lane];
    float4 vb;
    vb.x = (p0.x + p1.x) + (p2.x + p3.x);
    vb.y = (p0.y + p1.y) + (p2.y + p3.y);
    vb.z = (p0.z + p1.z) + (p2.z + p3.z);
    vb.w = (p0.w + p1.w) + (p2.w + p3.w);
    size_t bi = (size_t)b * NN + i;
    float4 nv = ((const float4*)(nf3 + bi * Cc))[lane];
    float val = nv.x*vb.x + nv.y*vb.y + nv.z*vb.z + nv.w*vb.w;
    if (lane < 9) val += pos[bi * 9 + lane] * w[NN + lane];
    val = wave_reduce_sum(val);
    float att = 1.f / (1.f + expf(-(val + nb[0])));
    float4 xo = ((const float4*)(x2 + bi * Cc))[lane];
    xo.x *= att; xo.y *= att; xo.z *= att; xo.w *= att;
    ((float4*)(out + bi * Cc))[lane] = xo;
}

// ---------------- launcher ----------------
extern "C" void kernel_launch(void* const* d_in, const int* in_sizes, int n_in,
                              void* d_out, int out_size, void* d_ws, size_t ws_size,
                              hipStream_t stream) {
    (void)in_sizes; (void)n_in; (void)out_size; (void)ws_size;
    const float* lf       = (const float*)d_in[0];
    const float* pos      = (const float*)d_in[2];
    const float* dp_adj_w = (const float*)d_in[3];
    const float* dp_aff_w = (const float*)d_in[4];
    const float* dp_aff_b = (const float*)d_in[5];
    const float* dp_ln_g  = (const float*)d_in[6];
    const float* dp_ln_b  = (const float*)d_in[7];
    const float* fa_adj_w = (const float*)d_in[8];
    const float* fa_aff_w = (const float*)d_in[9];
    const float* fa_aff_b = (const float*)d_in[10];
    const float* fa_ln_g  = (const float*)d_in[11];
    const float* fa_ln_b  = (const float*)d_in[12];
    const float* na_w     = (const float*)d_in[13];
    const float* na_b     = (const float*)d_in[14];
    float* out = (float*)d_out;
    float* ws  = (float*)d_ws;

    float* nfT = ws;                   // Bn*Cc*JP (reused stage 2)
    float* M   = nfT + Bn * Cc * JP;   // RR*Cc (reused for M2)
    float* P   = M   + RR * Cc;        // RR*Cc (reused for lf2)
    float* x1  = P   + RR * Cc;        // RR*Cc
    float* x2  = x1  + RR * Cc;        // RR*Cc
    float* nf3 = x2  + RR * Cc;        // RR*Cc
    float* WT1 = nf3 + RR * Cc;        // Cc*Cc
    float* WT2 = WT1 + Cc * Cc;        // Cc*Cc

    dim3 blk(256);
    k_tr  <<<128,       blk, 0, stream>>>(dp_aff_w, fa_aff_w, WT1, WT2);
    k_pre <<<RR/4 * 2,  blk, 0, stream>>>(lf, dp_adj_w, WT1, nfT, M, P);
    k_row1<<<Bn * NN/2, blk, 0, stream>>>(nfT, M, P, dp_aff_b, dp_ln_g, dp_ln_b, x1);
    k_mid <<<RR/4 * 2,  blk, 0, stream>>>(x1, fa_adj_w, WT2, fa_aff_b, nfT, M, P);
    k_row2<<<Bn * NN/2, blk, 0, stream>>>(nfT, M, P, fa_ln_g, fa_ln_b, x2, nf3);
    k_natt<<<Bn * NN/4, blk, 0, stream>>>(x2, nf3, pos, na_w, na_b, out);
}

// Round 6
// 91.195 us; speedup vs baseline: 1.2273x; 1.0694x over previous
//
#include <hip/hip_runtime.h>
#include <math.h>

#define Bn 8
#define NN 200
#define Cc 256
#define RR (Bn*NN)       // 1600 rows total
#define JP 200           // j-stride of transposed nf
#define N_EPS 1e-12f
#define LN_EPS 1e-5f
#define SLOPE 0.01f
#define SCALE 5.0f

// ---------------- reduction helpers ----------------
__device__ __forceinline__ float wave_reduce_sum(float v) {
    #pragma unroll
    for (int o = 32; o > 0; o >>= 1) v += __shfl_xor(v, o);
    return v;
}

// packed two-value reductions over ONE HALF (256 threads) of a 512-thread block.
// sh must hold 16 floats. h = half index (threadIdx.x>>8).
__device__ __forceinline__ float2 half_reduce_sum2(float2 v, float* sh, int h) {
    __syncthreads();
    #pragma unroll
    for (int o = 32; o > 0; o >>= 1) { v.x += __shfl_xor(v.x, o); v.y += __shfl_xor(v.y, o); }
    int w = threadIdx.x >> 6;                       // 0..7
    if ((threadIdx.x & 63) == 0) { sh[w*2] = v.x; sh[w*2+1] = v.y; }
    __syncthreads();
    int b0 = h * 8;
    return make_float2(sh[b0]+sh[b0+2]+sh[b0+4]+sh[b0+6],
                       sh[b0+1]+sh[b0+3]+sh[b0+5]+sh[b0+7]);
}

__device__ __forceinline__ float2 half_reduce_max2(float2 v, float* sh, int h) {
    __syncthreads();
    #pragma unroll
    for (int o = 32; o > 0; o >>= 1) {
        v.x = fmaxf(v.x, __shfl_xor(v.x, o));
        v.y = fmaxf(v.y, __shfl_xor(v.y, o));
    }
    int w = threadIdx.x >> 6;
    if ((threadIdx.x & 63) == 0) { sh[w*2] = v.x; sh[w*2+1] = v.y; }
    __syncthreads();
    int b0 = h * 8;
    return make_float2(fmaxf(fmaxf(sh[b0],sh[b0+2]), fmaxf(sh[b0+4],sh[b0+6])),
                       fmaxf(fmaxf(sh[b0+1],sh[b0+3]), fmaxf(sh[b0+5],sh[b0+7])));
}

// ---------------- 4-row GEMM building blocks (256-thr blocks) ----------------
__device__ __forceinline__ void gemm4_normT(int blk, const float* __restrict__ X,
        const float* __restrict__ W, float* __restrict__ nfT, float* __restrict__ Y,
        float* smem) {
    float (*sx)[Cc] = (float(*)[Cc])smem;
    int t = threadIdx.x, lane = t & 63, wv = t >> 6;
    int r0 = blk * 4;
    float4 x = ((const float4*)(X + (size_t)(r0 + wv) * Cc))[lane];
    float ss = wave_reduce_sum(x.x*x.x + x.y*x.y + x.z*x.z + x.w*x.w);
    float inv = 1.f / fmaxf(sqrtf(ss), N_EPS);
    x.x *= inv; x.y *= inv; x.z *= inv; x.w *= inv;
    ((float4*)&sx[wv][0])[lane] = x;
    __syncthreads();
    int b = r0 / NN, i0 = r0 % NN;
    float4 col;
    col.x = sx[0][t]; col.y = sx[1][t]; col.z = sx[2][t]; col.w = sx[3][t];
    *((float4*)(nfT + (size_t)b * Cc * JP + (size_t)t * JP + i0)) = col;
    float a0 = 0.f, a1 = 0.f, a2 = 0.f, a3 = 0.f;
    #pragma unroll 8
    for (int c = 0; c < Cc; c++) {
        float w = W[(size_t)c * Cc + t];
        a0 = fmaf(sx[0][c], w, a0);
        a1 = fmaf(sx[1][c], w, a1);
        a2 = fmaf(sx[2][c], w, a2);
        a3 = fmaf(sx[3][c], w, a3);
    }
    Y[(size_t)(r0+0)*Cc + t] = a0;
    Y[(size_t)(r0+1)*Cc + t] = a1;
    Y[(size_t)(r0+2)*Cc + t] = a2;
    Y[(size_t)(r0+3)*Cc + t] = a3;
}

__device__ __forceinline__ void gemm4_plain(int blk, const float* __restrict__ X,
        const float* __restrict__ W, const float* __restrict__ bias, float* __restrict__ Y,
        float* smem) {
    float (*sx)[Cc] = (float(*)[Cc])smem;
    int t = threadIdx.x, lane = t & 63, wv = t >> 6;
    int r0 = blk * 4;
    float4 x = ((const float4*)(X + (size_t)(r0 + wv) * Cc))[lane];
    ((float4*)&sx[wv][0])[lane] = x;
    __syncthreads();
    float a0 = 0.f, a1 = 0.f, a2 = 0.f, a3 = 0.f;
    #pragma unroll 8
    for (int c = 0; c < Cc; c++) {
        float w = W[(size_t)c * Cc + t];
        a0 = fmaf(sx[0][c], w, a0);
        a1 = fmaf(sx[1][c], w, a1);
        a2 = fmaf(sx[2][c], w, a2);
        a3 = fmaf(sx[3][c], w, a3);
    }
    if (bias) { float bv = bias[t]; a0 += bv; a1 += bv; a2 += bv; a3 += bv; }
    Y[(size_t)(r0+0)*Cc + t] = a0;
    Y[(size_t)(r0+1)*Cc + t] = a1;
    Y[(size_t)(r0+2)*Cc + t] = a2;
    Y[(size_t)(r0+3)*Cc + t] = a3;
}

// ---------------- dispatch 0: transpose dp_aff_w (WT1) + fa_aff_w (WT2) ----------------
__global__ void k_tr(const float* __restrict__ dp_aff_w, const float* __restrict__ fa_aff_w,
                     float* __restrict__ WT1, float* __restrict__ WT2) {
    __shared__ float tile[32][33];
    int tb = blockIdx.x;
    const float* S; float* D;
    if (tb < 64) { S = dp_aff_w; D = WT1; } else { S = fa_aff_w; D = WT2; tb -= 64; }
    int bx = tb & 7, by = tb >> 3;
    int tx = threadIdx.x & 31, ty = threadIdx.x >> 5;
    #pragma unroll
    for (int k = 0; k < 32; k += 8)
        tile[ty + k][tx] = S[(size_t)(by*32 + ty + k) * Cc + bx*32 + tx];
    __syncthreads();
    #pragma unroll
    for (int k = 0; k < 32; k += 8)
        D[(size_t)(bx*32 + ty + k) * Cc + by*32 + tx] = tile[tx][ty + k];
}

// ---------------- dispatch 1: nfT + M + P ----------------
__global__ void k_pre(const float* __restrict__ lf, const float* __restrict__ dp_adj_w,
                      const float* __restrict__ WT1,
                      float* __restrict__ nfT, float* __restrict__ M, float* __restrict__ P) {
    __shared__ float smem[4*Cc];
    int bid = blockIdx.x;
    if (bid < RR/4) gemm4_normT(bid, lf, dp_adj_w, nfT, M, smem);
    else            gemm4_plain(bid - RR/4, lf, WT1, nullptr, P, smem);
}

// ---------------- dispatch 2: fused diff_prop rows + stage-2 GEMVs ----------------
// 512 threads, 4 rows. half h handles rows i0+2h, i0+2h+1.
// b = bid&7 (XCD locality), i0 = (bid>>3)*4.
__global__ void k_row1f(const float* __restrict__ nfT, const float* __restrict__ M,
                        const float* __restrict__ P, const float* __restrict__ dp_aff_b,
                        const float* __restrict__ g, const float* __restrict__ bb,
                        const float* __restrict__ fa_adj_w, const float* __restrict__ WT2,
                        const float* __restrict__ fa_aff_b,
                        float* __restrict__ nfT2, float* __restrict__ M2,
                        float* __restrict__ lf2) {
    __shared__ float sm[4][Cc];
    __shared__ float sa[4][NN];
    __shared__ float su[4][Cc];
    __shared__ float sh[16];
    __shared__ float sinv[4];
    int t = threadIdx.x;
    int h = t >> 8, tt = t & 255;
    int b = blockIdx.x & 7;
    int i0 = (blockIdx.x >> 3) * 4;
    int r0 = i0 + 2*h, r1 = r0 + 1;
    size_t base = (size_t)b * NN * Cc;
    sm[2*h][tt]   = M[base + (size_t)r0 * Cc + tt];
    sm[2*h+1][tt] = M[base + (size_t)r1 * Cc + tt];
    __syncthreads();
    // phase A: A[r,j] for j=tt (both halves read same nfT addresses -> L1 share)
    if (tt < NN) {
        const float* nfc = nfT + (size_t)b * Cc * JP + tt;
        float a0 = 0.f, a1 = 0.f;
        #pragma unroll 8
        for (int c = 0; c < Cc; c++) {
            float q = nfc[(size_t)c * JP];
            a0 = fmaf(sm[2*h][c], q, a0);
            a1 = fmaf(sm[2*h+1][c], q, a1);
        }
        sa[2*h][tt] = a0; sa[2*h+1][tt] = a1;
    }
    // phase B: exp(5*(a-max)), zero diag, L1 norm; s = sum/max(sum,eps)
    float2 vm;
    vm.x = (tt < NN) ? sa[2*h][tt]   : -INFINITY;
    vm.y = (tt < NN) ? sa[2*h+1][tt] : -INFINITY;
    float2 m = half_reduce_max2(vm, sh, h);
    float e0 = (tt < NN && tt != r0) ? expf(SCALE * (vm.x - m.x)) : 0.f;
    float e1 = (tt < NN && tt != r1) ? expf(SCALE * (vm.y - m.y)) : 0.f;
    float2 sum = half_reduce_sum2(make_float2(e0, e1), sh, h);
    float A0 = e0 / fmaxf(sum.x, N_EPS);
    float A1 = e1 / fmaxf(sum.y, N_EPS);
    if (tt < NN) { sa[2*h][tt] = A0; sa[2*h+1][tt] = A1; }
    float s0 = sum.x / fmaxf(sum.x, N_EPS);
    float s1 = sum.y / fmaxf(sum.y, N_EPS);
    __syncthreads();
    // phase C: y = s*(P_r + bias) - sum_j a_j P_j (both halves same P addresses)
    const float* Pb = P + base;
    float acc0 = 0.f, acc1 = 0.f;
    #pragma unroll 8
    for (int j = 0; j < NN; j++) {
        float pv = Pb[(size_t)j * Cc + tt];
        acc0 = fmaf(sa[2*h][j], pv, acc0);
        acc1 = fmaf(sa[2*h+1][j], pv, acc1);
    }
    float bv = dp_aff_b[tt];
    float y0 = fmaf(s0, Pb[(size_t)r0 * Cc + tt] + bv, -acc0);
    float y1 = fmaf(s1, Pb[(size_t)r1 * Cc + tt] + bv, -acc1);
    // LayerNorm + LeakyReLU -> x1 rows (LDS only)
    float gg = g[tt], bbv = bb[tt];
    float2 mean2 = half_reduce_sum2(make_float2(y0, y1), sh, h);
    float d0 = y0 - mean2.x * (1.f/256.f);
    float d1 = y1 - mean2.y * (1.f/256.f);
    float2 var2 = half_reduce_sum2(make_float2(d0*d0, d1*d1), sh, h);
    float z0 = d0 / sqrtf(var2.x * (1.f/256.f) + LN_EPS) * gg + bbv;
    float z1 = d1 / sqrtf(var2.y * (1.f/256.f) + LN_EPS) * gg + bbv;
    z0 = (z0 >= 0.f) ? z0 : SLOPE * z0;
    z1 = (z1 >= 0.f) ? z1 : SLOPE * z1;
    su[2*h][tt] = z0; su[2*h+1][tt] = z1;
    // stage-2 l2norm factors
    float2 ss2 = half_reduce_sum2(make_float2(z0*z0, z1*z1), sh, h);
    if (tt == 0) {
        sinv[2*h]   = 1.f / fmaxf(sqrtf(ss2.x), N_EPS);
        sinv[2*h+1] = 1.f / fmaxf(sqrtf(ss2.y), N_EPS);
    }
    __syncthreads();
    // nf2 transposed write (half 0 only): float4 over the 4 consecutive rows
    if (h == 0) {
        float4 col;
        col.x = su[0][tt] * sinv[0];
        col.y = su[1][tt] * sinv[1];
        col.z = su[2][tt] * sinv[2];
        col.w = su[3][tt] * sinv[3];
        *((float4*)(nfT2 + (size_t)b * Cc * JP + (size_t)tt * JP + i0)) = col;
    }
    // fused stage-2 GEMVs: M2 = l2norm(x1)@fa_adj_w (scale folded), lf2 = x1@WT2 + b
    float m0 = 0.f, m1 = 0.f, l0 = 0.f, l1 = 0.f;
    #pragma unroll 8
    for (int c = 0; c < Cc; c++) {
        float wa = fa_adj_w[(size_t)c * Cc + tt];
        float wl = WT2[(size_t)c * Cc + tt];
        float u0 = su[2*h][c], u1 = su[2*h+1][c];
        m0 = fmaf(u0, wa, m0); m1 = fmaf(u1, wa, m1);
        l0 = fmaf(u0, wl, l0); l1 = fmaf(u1, wl, l1);
    }
    float fb = fa_aff_b[tt];
    M2 [base + (size_t)r0 * Cc + tt] = m0 * sinv[2*h];
    M2 [base + (size_t)r1 * Cc + tt] = m1 * sinv[2*h+1];
    lf2[base + (size_t)r0 * Cc + tt] = l0 + fb;
    lf2[base + (size_t)r1 * Cc + tt] = l1 + fb;
}

// ---------------- dispatch 3: feat_aggr rows (4 rows, 512 thr) + nf3 epilogue ----------------
__global__ void k_row2f(const float* __restrict__ nfT2, const float* __restrict__ M2,
                        const float* __restrict__ lf2, const float* __restrict__ g,
                        const float* __restrict__ bb, float* __restrict__ x2,
                        float* __restrict__ nf3) {
    __shared__ float sm[4][Cc];
    __shared__ float sa[4][NN];
    __shared__ float sh[16];
    int t = threadIdx.x;
    int h = t >> 8, tt = t & 255;
    int b = blockIdx.x & 7;
    int i0 = (blockIdx.x >> 3) * 4;
    int r0 = i0 + 2*h, r1 = r0 + 1;
    size_t base = (size_t)b * NN * Cc;
    sm[2*h][tt]   = M2[base + (size_t)r0 * Cc + tt];
    sm[2*h+1][tt] = M2[base + (size_t)r1 * Cc + tt];
    __syncthreads();
    if (tt < NN) {
        const float* nfc = nfT2 + (size_t)b * Cc * JP + tt;
        float a0 = 0.f, a1 = 0.f;
        #pragma unroll 8
        for (int c = 0; c < Cc; c++) {
            float q = nfc[(size_t)c * JP];
            a0 = fmaf(sm[2*h][c], q, a0);
            a1 = fmaf(sm[2*h+1][c], q, a1);
        }
        sa[2*h][tt] = a0; sa[2*h+1][tt] = a1;
    }
    // softmax
    float2 vm;
    vm.x = (tt < NN) ? sa[2*h][tt]   : -INFINITY;
    vm.y = (tt < NN) ? sa[2*h+1][tt] : -INFINITY;
    float2 m = half_reduce_max2(vm, sh, h);
    float e0 = (tt < NN) ? expf(SCALE * (vm.x - m.x)) : 0.f;
    float e1 = (tt < NN) ? expf(SCALE * (vm.y - m.y)) : 0.f;
    float2 sum = half_reduce_sum2(make_float2(e0, e1), sh, h);
    if (tt < NN) { sa[2*h][tt] = e0 / sum.x; sa[2*h+1][tt] = e1 / sum.y; }
    __syncthreads();
    // y = A @ lf2
    const float* l2b = lf2 + base;
    float y0 = 0.f, y1 = 0.f;
    #pragma unroll 8
    for (int j = 0; j < NN; j++) {
        float xv = l2b[(size_t)j * Cc + tt];
        y0 = fmaf(sa[2*h][j], xv, y0);
        y1 = fmaf(sa[2*h+1][j], xv, y1);
    }
    // LN + leaky + l2norm epilogue
    float gg = g[tt], bbv = bb[tt];
    float2 mean2 = half_reduce_sum2(make_float2(y0, y1), sh, h);
    float d0 = y0 - mean2.x * (1.f/256.f);
    float d1 = y1 - mean2.y * (1.f/256.f);
    float2 var2 = half_reduce_sum2(make_float2(d0*d0, d1*d1), sh, h);
    float z0 = d0 / sqrtf(var2.x * (1.f/256.f) + LN_EPS) * gg + bbv;
    float z1 = d1 / sqrtf(var2.y * (1.f/256.f) + LN_EPS) * gg + bbv;
    z0 = (z0 >= 0.f) ? z0 : SLOPE * z0;
    z1 = (z1 >= 0.f) ? z1 : SLOPE * z1;
    x2[base + (size_t)r0 * Cc + tt] = z0;
    x2[base + (size_t)r1 * Cc + tt] = z1;
    float2 ss2 = half_reduce_sum2(make_float2(z0*z0, z1*z1), sh, h);
    nf3[base + (size_t)r0 * Cc + tt] = z0 / fmaxf(sqrtf(ss2.x), N_EPS);
    nf3[base + (size_t)r1 * Cc + tt] = z1 / fmaxf(sqrtf(ss2.y), N_EPS);
}

// ---------------- dispatch 4: fused wsum + node_att (4 rows/block, 256 thr) ----------------
__global__ void k_natt(const float* __restrict__ x2, const float* __restrict__ nf3,
                       const float* __restrict__ pos, const float* __restrict__ w,
                       const float* __restrict__ nb, float* __restrict__ out) {
    __shared__ float svb[4][Cc];
    int t = threadIdx.x, lane = t & 63, wv = t >> 6;
    int b = blockIdx.x & 7;
    int i = (blockIdx.x >> 3) * 4 + wv;
    const float4* slab = (const float4*)(nf3 + (size_t)b * NN * Cc);
    float4 acc = make_float4(0.f, 0.f, 0.f, 0.f);
    for (int j = wv * 50; j < wv * 50 + 50; j++) {
        float4 q = slab[j * 64 + lane];
        float wj = w[j];
        acc.x = fmaf(wj, q.x, acc.x);
        acc.y = fmaf(wj, q.y, acc.y);
        acc.z = fmaf(wj, q.z, acc.z);
        acc.w = fmaf(wj, q.w, acc.w);
    }
    ((float4*)&svb[wv][0])[lane] = acc;
    __syncthreads();
    float4 p0 = ((const float4*)&svb[0][0])[lane];
    float4 p1 = ((const float4*)&svb[1][0])[lane];
    float4 p2 = ((const float4*)&svb[2][0])[lane];
    float4 p3 = ((const float4*)&svb[3][0])[lane];
    float4 vb;
    vb.x = (p0.x + p1.x) + (p2.x + p3.x);
    vb.y = (p0.y + p1.y) + (p2.y + p3.y);
    vb.z = (p0.z + p1.z) + (p2.z + p3.z);
    vb.w = (p0.w + p1.w) + (p2.w + p3.w);
    size_t bi = (size_t)b * NN + i;
    float4 nv = ((const float4*)(nf3 + bi * Cc))[lane];
    float val = nv.x*vb.x + nv.y*vb.y + nv.z*vb.z + nv.w*vb.w;
    if (lane < 9) val += pos[bi * 9 + lane] * w[NN + lane];
    val = wave_reduce_sum(val);
    float att = 1.f / (1.f + expf(-(val + nb[0])));
    float4 xo = ((const float4*)(x2 + bi * Cc))[lane];
    xo.x *= att; xo.y *= att; xo.z *= att; xo.w *= att;
    ((float4*)(out + bi * Cc))[lane] = xo;
}

// ---------------- launcher ----------------
extern "C" void kernel_launch(void* const* d_in, const int* in_sizes, int n_in,
                              void* d_out, int out_size, void* d_ws, size_t ws_size,
                              hipStream_t stream) {
    (void)in_sizes; (void)n_in; (void)out_size; (void)ws_size;
    const float* lf       = (const float*)d_in[0];
    const float* pos      = (const float*)d_in[2];
    const float* dp_adj_w = (const float*)d_in[3];
    const float* dp_aff_w = (const float*)d_in[4];
    const float* dp_aff_b = (const float*)d_in[5];
    const float* dp_ln_g  = (const float*)d_in[6];
    const float* dp_ln_b  = (const float*)d_in[7];
    const float* fa_adj_w = (const float*)d_in[8];
    const float* fa_aff_w = (const float*)d_in[9];
    const float* fa_aff_b = (const float*)d_in[10];
    const float* fa_ln_g  = (const float*)d_in[11];
    const float* fa_ln_b  = (const float*)d_in[12];
    const float* na_w     = (const float*)d_in[13];
    const float* na_b     = (const float*)d_in[14];
    float* out = (float*)d_out;
    float* ws  = (float*)d_ws;

    float* nfT  = ws;                    // Bn*Cc*JP
    float* nfT2 = nfT  + Bn * Cc * JP;   // Bn*Cc*JP
    float* M    = nfT2 + Bn * Cc * JP;   // RR*Cc  (M2 written in-place)
    float* P    = M    + RR * Cc;        // RR*Cc
    float* lf2  = P    + RR * Cc;        // RR*Cc
    float* x2   = lf2  + RR * Cc;        // RR*Cc
    float* nf3  = x2   + RR * Cc;        // RR*Cc
    float* WT1  = nf3  + RR * Cc;        // Cc*Cc
    float* WT2  = WT1  + Cc * Cc;        // Cc*Cc

    k_tr   <<<128,        dim3(256), 0, stream>>>(dp_aff_w, fa_aff_w, WT1, WT2);
    k_pre  <<<RR/4 * 2,   dim3(256), 0, stream>>>(lf, dp_adj_w, WT1, nfT, M, P);
    k_row1f<<<Bn * NN/4,  dim3(512), 0, stream>>>(nfT, M, P, dp_aff_b, dp_ln_g, dp_ln_b,
                                                  fa_adj_w, WT2, fa_aff_b, nfT2, M, lf2);
    k_row2f<<<Bn * NN/4,  dim3(512), 0, stream>>>(nfT2, M, lf2, fa_ln_g, fa_ln_b, x2, nf3);
    k_natt <<<Bn * NN/4,  dim3(256), 0, stream>>>(x2, nf3, pos, na_w, na_b, out);
}

// Round 7
// 83.951 us; speedup vs baseline: 1.3332x; 1.0863x over previous
//
#include <hip/hip_runtime.h>
#include <math.h>

#define Bn 8
#define NN 200
#define Cc 256
#define RR (Bn*NN)       // 1600 rows total
#define JP 200           // j-stride of transposed nf
#define N_EPS 1e-12f
#define LN_EPS 1e-5f
#define SLOPE 0.01f
#define SCALE 5.0f

// ---------------- reduction helpers ----------------
__device__ __forceinline__ float wave_reduce_sum(float v) {
    #pragma unroll
    for (int o = 32; o > 0; o >>= 1) v += __shfl_xor(v, o);
    return v;
}

// packed two-value reductions over ONE HALF (256 threads) of a 512-thread block.
// sh must hold 16 floats. h = half index (threadIdx.x>>8). ALL 512 threads must call.
__device__ __forceinline__ float2 half_reduce_sum2(float2 v, float* sh, int h) {
    __syncthreads();
    #pragma unroll
    for (int o = 32; o > 0; o >>= 1) { v.x += __shfl_xor(v.x, o); v.y += __shfl_xor(v.y, o); }
    int w = threadIdx.x >> 6;                       // 0..7
    if ((threadIdx.x & 63) == 0) { sh[w*2] = v.x; sh[w*2+1] = v.y; }
    __syncthreads();
    int b0 = h * 8;
    return make_float2(sh[b0]+sh[b0+2]+sh[b0+4]+sh[b0+6],
                       sh[b0+1]+sh[b0+3]+sh[b0+5]+sh[b0+7]);
}

__device__ __forceinline__ float2 half_reduce_max2(float2 v, float* sh, int h) {
    __syncthreads();
    #pragma unroll
    for (int o = 32; o > 0; o >>= 1) {
        v.x = fmaxf(v.x, __shfl_xor(v.x, o));
        v.y = fmaxf(v.y, __shfl_xor(v.y, o));
    }
    int w = threadIdx.x >> 6;
    if ((threadIdx.x & 63) == 0) { sh[w*2] = v.x; sh[w*2+1] = v.y; }
    __syncthreads();
    int b0 = h * 8;
    return make_float2(fmaxf(fmaxf(sh[b0],sh[b0+2]), fmaxf(sh[b0+4],sh[b0+6])),
                       fmaxf(fmaxf(sh[b0+1],sh[b0+3]), fmaxf(sh[b0+5],sh[b0+7])));
}

// ---------------- dispatch 0: transpose dp_aff_w (WT1) + fa_aff_w (WT2) ----------------
__global__ void k_tr(const float* __restrict__ dp_aff_w, const float* __restrict__ fa_aff_w,
                     float* __restrict__ WT1, float* __restrict__ WT2) {
    __shared__ float tile[32][33];
    int tb = blockIdx.x;
    const float* S; float* D;
    if (tb < 64) { S = dp_aff_w; D = WT1; } else { S = fa_aff_w; D = WT2; tb -= 64; }
    int bx = tb & 7, by = tb >> 3;
    int tx = threadIdx.x & 31, ty = threadIdx.x >> 5;
    #pragma unroll
    for (int k = 0; k < 32; k += 8)
        tile[ty + k][tx] = S[(size_t)(by*32 + ty + k) * Cc + bx*32 + tx];
    __syncthreads();
    #pragma unroll
    for (int k = 0; k < 32; k += 8)
        D[(size_t)(bx*32 + ty + k) * Cc + by*32 + tx] = tile[tx][ty + k];
}

// ---------------- dispatch 1: 8-row GEMM blocks — nfT + M (norm branch), P (plain) ----------------
__global__ void k_pre(const float* __restrict__ lf, const float* __restrict__ dp_adj_w,
                      const float* __restrict__ WT1,
                      float* __restrict__ nfT, float* __restrict__ M, float* __restrict__ P) {
    __shared__ float sx[8][Cc];
    int bid = blockIdx.x;
    int t = threadIdx.x, lane = t & 63, wv = t >> 6;
    if (bid < RR/8) {
        int r0 = bid * 8;
        #pragma unroll
        for (int k = 0; k < 2; k++) {
            int r = 2*wv + k;
            float4 x = ((const float4*)(lf + (size_t)(r0 + r) * Cc))[lane];
            float ss = wave_reduce_sum(x.x*x.x + x.y*x.y + x.z*x.z + x.w*x.w);
            float inv = 1.f / fmaxf(sqrtf(ss), N_EPS);
            x.x *= inv; x.y *= inv; x.z *= inv; x.w *= inv;
            ((float4*)&sx[r][0])[lane] = x;
        }
        __syncthreads();
        int b = r0 / NN, i0 = r0 % NN;
        float4 cA, cB;
        cA.x = sx[0][t]; cA.y = sx[1][t]; cA.z = sx[2][t]; cA.w = sx[3][t];
        cB.x = sx[4][t]; cB.y = sx[5][t]; cB.z = sx[6][t]; cB.w = sx[7][t];
        float* np = nfT + (size_t)b * Cc * JP + (size_t)t * JP + i0;
        *((float4*)np) = cA;
        *((float4*)(np + 4)) = cB;
        float acc[8] = {0,0,0,0,0,0,0,0};
        #pragma unroll 4
        for (int c = 0; c < Cc; c++) {
            float w = dp_adj_w[(size_t)c * Cc + t];
            #pragma unroll
            for (int r = 0; r < 8; r++) acc[r] = fmaf(sx[r][c], w, acc[r]);
        }
        #pragma unroll
        for (int r = 0; r < 8; r++) M[(size_t)(r0 + r) * Cc + t] = acc[r];
    } else {
        int r0 = (bid - RR/8) * 8;
        #pragma unroll
        for (int k = 0; k < 2; k++) {
            int r = 2*wv + k;
            ((float4*)&sx[r][0])[lane] = ((const float4*)(lf + (size_t)(r0 + r) * Cc))[lane];
        }
        __syncthreads();
        float acc[8] = {0,0,0,0,0,0,0,0};
        #pragma unroll 4
        for (int c = 0; c < Cc; c++) {
            float w = WT1[(size_t)c * Cc + t];
            #pragma unroll
            for (int r = 0; r < 8; r++) acc[r] = fmaf(sx[r][c], w, acc[r]);
        }
        #pragma unroll
        for (int r = 0; r < 8; r++) P[(size_t)(r0 + r) * Cc + t] = acc[r];
    }
}

// ---------------- dispatch 2: fused diff_prop rows + stage-2 GEMVs (512 thr, 4 rows) ----------------
// b = bid&7 (XCD locality), i0 = (bid>>3)*4. h = thread half.
__global__ void k_row1f(const float* __restrict__ nfT, const float* __restrict__ Min,
                        const float* __restrict__ P, const float* __restrict__ dp_aff_b,
                        const float* __restrict__ g, const float* __restrict__ bb,
                        const float* __restrict__ fa_adj_w, const float* __restrict__ WT2,
                        const float* __restrict__ fa_aff_b,
                        float* __restrict__ nfT2, float* __restrict__ M2,
                        float* __restrict__ lf2) {
    __shared__ float sm[4][Cc];      // M rows
    __shared__ float sap[2][4][NN];  // phase-A partials
    __shared__ float sa[4][NN];      // attention rows
    __shared__ float sup[2][4][Cc];  // phase-C partials
    __shared__ float su[4][Cc];      // x1 rows
    __shared__ float sh[16];
    __shared__ float sinv[4];
    int t = threadIdx.x, h = t >> 8, tt = t & 255;
    int b = blockIdx.x & 7;
    int i0 = (blockIdx.x >> 3) * 4;
    size_t base = (size_t)b * NN * Cc;
    {   // load 4 M rows (contiguous 1024 floats)
        const float* src = Min + base + (size_t)i0 * Cc;
        float* dst = &sm[0][0];
        dst[t] = src[t];
        dst[t + 512] = src[t + 512];
    }
    __syncthreads();
    // phase A: c-split dots — each half does ALL 4 rows over half the c-range
    if (tt < NN) {
        const float* nfc = nfT + (size_t)b * Cc * JP + tt;
        int c0 = h * 128;
        float a0=0.f, a1=0.f, a2=0.f, a3=0.f;
        #pragma unroll 8
        for (int c = c0; c < c0 + 128; c++) {
            float q = nfc[(size_t)c * JP];
            a0 = fmaf(sm[0][c], q, a0); a1 = fmaf(sm[1][c], q, a1);
            a2 = fmaf(sm[2][c], q, a2); a3 = fmaf(sm[3][c], q, a3);
        }
        sap[h][0][tt]=a0; sap[h][1][tt]=a1; sap[h][2][tt]=a2; sap[h][3][tt]=a3;
    }
    __syncthreads();
    // phase B: half h owns rows lr0=2h, lr1=2h+1
    int lr0 = 2*h, lr1 = 2*h + 1;
    float2 vm;
    vm.x = (tt < NN) ? sap[0][lr0][tt] + sap[1][lr0][tt] : -INFINITY;
    vm.y = (tt < NN) ? sap[0][lr1][tt] + sap[1][lr1][tt] : -INFINITY;
    float2 m = half_reduce_max2(vm, sh, h);
    float e0 = (tt < NN && tt != i0 + lr0) ? expf(SCALE * (vm.x - m.x)) : 0.f;
    float e1 = (tt < NN && tt != i0 + lr1) ? expf(SCALE * (vm.y - m.y)) : 0.f;
    float2 sum = half_reduce_sum2(make_float2(e0, e1), sh, h);
    if (tt < NN) {
        sa[lr0][tt] = e0 / fmaxf(sum.x, N_EPS);
        sa[lr1][tt] = e1 / fmaxf(sum.y, N_EPS);
    }
    float s0 = sum.x / fmaxf(sum.x, N_EPS);
    float s1 = sum.y / fmaxf(sum.y, N_EPS);
    __syncthreads();
    // phase C: j-split — each half does ALL 4 rows over half the j-range
    const float* Pb = P + base;
    {
        float q0=0.f, q1=0.f, q2=0.f, q3=0.f;
        int j0 = h * 100;
        #pragma unroll 4
        for (int j = j0; j < j0 + 100; j++) {
            float pv = Pb[(size_t)j * Cc + tt];
            q0 = fmaf(sa[0][j], pv, q0); q1 = fmaf(sa[1][j], pv, q1);
            q2 = fmaf(sa[2][j], pv, q2); q3 = fmaf(sa[3][j], pv, q3);
        }
        sup[h][0][tt]=q0; sup[h][1][tt]=q1; sup[h][2][tt]=q2; sup[h][3][tt]=q3;
    }
    __syncthreads();
    float bv = dp_aff_b[tt];
    float acc0 = sup[0][lr0][tt] + sup[1][lr0][tt];
    float acc1 = sup[0][lr1][tt] + sup[1][lr1][tt];
    float y0 = fmaf(s0, Pb[(size_t)(i0 + lr0) * Cc + tt] + bv, -acc0);
    float y1 = fmaf(s1, Pb[(size_t)(i0 + lr1) * Cc + tt] + bv, -acc1);
    // LayerNorm + LeakyReLU (per half, 2 rows packed)
    float gg = g[tt], bbv = bb[tt];
    float2 mean2 = half_reduce_sum2(make_float2(y0, y1), sh, h);
    float d0 = y0 - mean2.x * (1.f/256.f);
    float d1 = y1 - mean2.y * (1.f/256.f);
    float2 var2 = half_reduce_sum2(make_float2(d0*d0, d1*d1), sh, h);
    float z0 = d0 / sqrtf(var2.x * (1.f/256.f) + LN_EPS) * gg + bbv;
    float z1 = d1 / sqrtf(var2.y * (1.f/256.f) + LN_EPS) * gg + bbv;
    z0 = (z0 >= 0.f) ? z0 : SLOPE * z0;
    z1 = (z1 >= 0.f) ? z1 : SLOPE * z1;
    su[lr0][tt] = z0; su[lr1][tt] = z1;
    float2 ss2 = half_reduce_sum2(make_float2(z0*z0, z1*z1), sh, h);
    if (tt == 0) {
        sinv[lr0] = 1.f / fmaxf(sqrtf(ss2.x), N_EPS);
        sinv[lr1] = 1.f / fmaxf(sqrtf(ss2.y), N_EPS);
    }
    __syncthreads();
    // phase D: matrix-split — h0: nfT2 write + M2 GEMV; h1: lf2 GEMV
    if (h == 0) {
        float4 col;
        col.x = su[0][tt] * sinv[0]; col.y = su[1][tt] * sinv[1];
        col.z = su[2][tt] * sinv[2]; col.w = su[3][tt] * sinv[3];
        *((float4*)(nfT2 + (size_t)b * Cc * JP + (size_t)tt * JP + i0)) = col;
        float m0=0.f, m1=0.f, m2r=0.f, m3=0.f;
        #pragma unroll 8
        for (int c = 0; c < Cc; c++) {
            float wa = fa_adj_w[(size_t)c * Cc + tt];
            m0 = fmaf(su[0][c], wa, m0); m1 = fmaf(su[1][c], wa, m1);
            m2r = fmaf(su[2][c], wa, m2r); m3 = fmaf(su[3][c], wa, m3);
        }
        M2[base + (size_t)(i0+0)*Cc + tt] = m0 * sinv[0];
        M2[base + (size_t)(i0+1)*Cc + tt] = m1 * sinv[1];
        M2[base + (size_t)(i0+2)*Cc + tt] = m2r * sinv[2];
        M2[base + (size_t)(i0+3)*Cc + tt] = m3 * sinv[3];
    } else {
        float l0=0.f, l1=0.f, l2=0.f, l3=0.f;
        #pragma unroll 8
        for (int c = 0; c < Cc; c++) {
            float wl = WT2[(size_t)c * Cc + tt];
            l0 = fmaf(su[0][c], wl, l0); l1 = fmaf(su[1][c], wl, l1);
            l2 = fmaf(su[2][c], wl, l2); l3 = fmaf(su[3][c], wl, l3);
        }
        float fb = fa_aff_b[tt];
        lf2[base + (size_t)(i0+0)*Cc + tt] = l0 + fb;
        lf2[base + (size_t)(i0+1)*Cc + tt] = l1 + fb;
        lf2[base + (size_t)(i0+2)*Cc + tt] = l2 + fb;
        lf2[base + (size_t)(i0+3)*Cc + tt] = l3 + fb;
    }
}

// ---------------- dispatch 3: feat_aggr rows (512 thr, 4 rows) + nf3 epilogue ----------------
__global__ void k_row2f(const float* __restrict__ nfT2, const float* __restrict__ M2,
                        const float* __restrict__ lf2, const float* __restrict__ g,
                        const float* __restrict__ bb, float* __restrict__ x2,
                        float* __restrict__ nf3) {
    __shared__ float sm[4][Cc];
    __shared__ float sap[2][4][NN];
    __shared__ float sa[4][NN];
    __shared__ float sup[2][4][Cc];
    __shared__ float sh[16];
    int t = threadIdx.x, h = t >> 8, tt = t & 255;
    int b = blockIdx.x & 7;
    int i0 = (blockIdx.x >> 3) * 4;
    size_t base = (size_t)b * NN * Cc;
    {
        const float* src = M2 + base + (size_t)i0 * Cc;
        float* dst = &sm[0][0];
        dst[t] = src[t];
        dst[t + 512] = src[t + 512];
    }
    __syncthreads();
    // phase A: c-split dots
    if (tt < NN) {
        const float* nfc = nfT2 + (size_t)b * Cc * JP + tt;
        int c0 = h * 128;
        float a0=0.f, a1=0.f, a2=0.f, a3=0.f;
        #pragma unroll 8
        for (int c = c0; c < c0 + 128; c++) {
            float q = nfc[(size_t)c * JP];
            a0 = fmaf(sm[0][c], q, a0); a1 = fmaf(sm[1][c], q, a1);
            a2 = fmaf(sm[2][c], q, a2); a3 = fmaf(sm[3][c], q, a3);
        }
        sap[h][0][tt]=a0; sap[h][1][tt]=a1; sap[h][2][tt]=a2; sap[h][3][tt]=a3;
    }
    __syncthreads();
    // softmax (no diag-zero), half h owns rows lr0, lr1
    int lr0 = 2*h, lr1 = 2*h + 1;
    float2 vm;
    vm.x = (tt < NN) ? sap[0][lr0][tt] + sap[1][lr0][tt] : -INFINITY;
    vm.y = (tt < NN) ? sap[0][lr1][tt] + sap[1][lr1][tt] : -INFINITY;
    float2 m = half_reduce_max2(vm, sh, h);
    float e0 = (tt < NN) ? expf(SCALE * (vm.x - m.x)) : 0.f;
    float e1 = (tt < NN) ? expf(SCALE * (vm.y - m.y)) : 0.f;
    float2 sum = half_reduce_sum2(make_float2(e0, e1), sh, h);
    if (tt < NN) { sa[lr0][tt] = e0 / sum.x; sa[lr1][tt] = e1 / sum.y; }
    __syncthreads();
    // phase C: j-split, y = A @ lf2
    const float* l2b = lf2 + base;
    {
        float q0=0.f, q1=0.f, q2=0.f, q3=0.f;
        int j0 = h * 100;
        #pragma unroll 4
        for (int j = j0; j < j0 + 100; j++) {
            float pv = l2b[(size_t)j * Cc + tt];
            q0 = fmaf(sa[0][j], pv, q0); q1 = fmaf(sa[1][j], pv, q1);
            q2 = fmaf(sa[2][j], pv, q2); q3 = fmaf(sa[3][j], pv, q3);
        }
        sup[h][0][tt]=q0; sup[h][1][tt]=q1; sup[h][2][tt]=q2; sup[h][3][tt]=q3;
    }
    __syncthreads();
    float y0 = sup[0][lr0][tt] + sup[1][lr0][tt];
    float y1 = sup[0][lr1][tt] + sup[1][lr1][tt];
    // LN + leaky + l2norm epilogue
    float gg = g[tt], bbv = bb[tt];
    float2 mean2 = half_reduce_sum2(make_float2(y0, y1), sh, h);
    float d0 = y0 - mean2.x * (1.f/256.f);
    float d1 = y1 - mean2.y * (1.f/256.f);
    float2 var2 = half_reduce_sum2(make_float2(d0*d0, d1*d1), sh, h);
    float z0 = d0 / sqrtf(var2.x * (1.f/256.f) + LN_EPS) * gg + bbv;
    float z1 = d1 / sqrtf(var2.y * (1.f/256.f) + LN_EPS) * gg + bbv;
    z0 = (z0 >= 0.f) ? z0 : SLOPE * z0;
    z1 = (z1 >= 0.f) ? z1 : SLOPE * z1;
    x2[base + (size_t)(i0 + lr0) * Cc + tt] = z0;
    x2[base + (size_t)(i0 + lr1) * Cc + tt] = z1;
    float2 ss2 = half_reduce_sum2(make_float2(z0*z0, z1*z1), sh, h);
    nf3[base + (size_t)(i0 + lr0) * Cc + tt] = z0 / fmaxf(sqrtf(ss2.x), N_EPS);
    nf3[base + (size_t)(i0 + lr1) * Cc + tt] = z1 / fmaxf(sqrtf(ss2.y), N_EPS);
}

// ---------------- dispatch 4: fused wsum + node_att (4 rows/block, 256 thr) ----------------
__global__ void k_natt(const float* __restrict__ x2, const float* __restrict__ nf3,
                       const float* __restrict__ pos, const float* __restrict__ w,
                       const float* __restrict__ nb, float* __restrict__ out) {
    __shared__ float svb[4][Cc];
    int t = threadIdx.x, lane = t & 63, wv = t >> 6;
    int b = blockIdx.x & 7;
    int i = (blockIdx.x >> 3) * 4 + wv;
    const float4* slab = (const float4*)(nf3 + (size_t)b * NN * Cc);
    float4 acc = make_float4(0.f, 0.f, 0.f, 0.f);
    for (int j = wv * 50; j < wv * 50 + 50; j++) {
        float4 q = slab[j * 64 + lane];
        float wj = w[j];
        acc.x = fmaf(wj, q.x, acc.x);
        acc.y = fmaf(wj, q.y, acc.y);
        acc.z = fmaf(wj, q.z, acc.z);
        acc.w = fmaf(wj, q.w, acc.w);
    }
    ((float4*)&svb[wv][0])[lane] = acc;
    __syncthreads();
    float4 p0 = ((const float4*)&svb[0][0])[lane];
    float4 p1 = ((const float4*)&svb[1][0])[lane];
    float4 p2 = ((const float4*)&svb[2][0])[lane];
    float4 p3 = ((const float4*)&svb[3][0])[lane];
    float4 vb;
    vb.x = (p0.x + p1.x) + (p2.x + p3.x);
    vb.y = (p0.y + p1.y) + (p2.y + p3.y);
    vb.z = (p0.z + p1.z) + (p2.z + p3.z);
    vb.w = (p0.w + p1.w) + (p2.w + p3.w);
    size_t bi = (size_t)b * NN + i;
    float4 nv = ((const float4*)(nf3 + bi * Cc))[lane];
    float val = nv.x*vb.x + nv.y*vb.y + nv.z*vb.z + nv.w*vb.w;
    if (lane < 9) val += pos[bi * 9 + lane] * w[NN + lane];
    val = wave_reduce_sum(val);
    float att = 1.f / (1.f + expf(-(val + nb[0])));
    float4 xo = ((const float4*)(x2 + bi * Cc))[lane];
    xo.x *= att; xo.y *= att; xo.z *= att; xo.w *= att;
    ((float4*)(out + bi * Cc))[lane] = xo;
}

// ---------------- launcher ----------------
extern "C" void kernel_launch(void* const* d_in, const int* in_sizes, int n_in,
                              void* d_out, int out_size, void* d_ws, size_t ws_size,
                              hipStream_t stream) {
    (void)in_sizes; (void)n_in; (void)out_size; (void)ws_size;
    const float* lf       = (const float*)d_in[0];
    const float* pos      = (const float*)d_in[2];
    const float* dp_adj_w = (const float*)d_in[3];
    const float* dp_aff_w = (const float*)d_in[4];
    const float* dp_aff_b = (const float*)d_in[5];
    const float* dp_ln_g  = (const float*)d_in[6];
    const float* dp_ln_b  = (const float*)d_in[7];
    const float* fa_adj_w = (const float*)d_in[8];
    const float* fa_aff_w = (const float*)d_in[9];
    const float* fa_aff_b = (const float*)d_in[10];
    const float* fa_ln_g  = (const float*)d_in[11];
    const float* fa_ln_b  = (const float*)d_in[12];
    const float* na_w     = (const float*)d_in[13];
    const float* na_b     = (const float*)d_in[14];
    float* out = (float*)d_out;
    float* ws  = (float*)d_ws;

    float* nfT  = ws;                    // Bn*Cc*JP
    float* nfT2 = nfT  + Bn * Cc * JP;   // Bn*Cc*JP
    float* M    = nfT2 + Bn * Cc * JP;   // RR*Cc  (M2 written in-place)
    float* P    = M    + RR * Cc;        // RR*Cc
    float* lf2  = P    + RR * Cc;        // RR*Cc
    float* x2   = lf2  + RR * Cc;        // RR*Cc
    float* nf3  = x2   + RR * Cc;        // RR*Cc
    float* WT1  = nf3  + RR * Cc;        // Cc*Cc
    float* WT2  = WT1  + Cc * Cc;        // Cc*Cc

    k_tr   <<<128,        dim3(256), 0, stream>>>(dp_aff_w, fa_aff_w, WT1, WT2);
    k_pre  <<<RR/8 * 2,   dim3(256), 0, stream>>>(lf, dp_adj_w, WT1, nfT, M, P);
    k_row1f<<<Bn * NN/4,  dim3(512), 0, stream>>>(nfT, M, P, dp_aff_b, dp_ln_g, dp_ln_b,
                                                  fa_adj_w, WT2, fa_aff_b, nfT2, M, lf2);
    k_row2f<<<Bn * NN/4,  dim3(512), 0, stream>>>(nfT2, M, lf2, fa_ln_g, fa_ln_b, x2, nf3);
    k_natt <<<Bn * NN/4,  dim3(256), 0, stream>>>(x2, nf3, pos, na_w, na_b, out);
}

// Round 8
// 70.605 us; speedup vs baseline: 1.5852x; 1.1890x over previous
//
#include <hip/hip_runtime.h>
#include <math.h>

#define Bn 8
#define NN 200
#define Cc 256
#define RR (Bn*NN)       // 1600 rows total
#define JP 200           // j-stride of transposed nf
#define N_EPS 1e-12f
#define LN_EPS 1e-5f
#define SLOPE 0.01f
#define SCALE 5.0f

#define FMA4(acc, s, v) { acc.x = fmaf((s), (v).x, acc.x); acc.y = fmaf((s), (v).y, acc.y); \
                          acc.z = fmaf((s), (v).z, acc.z); acc.w = fmaf((s), (v).w, acc.w); }

// ---------------- reduction helpers ----------------
__device__ __forceinline__ float wave_reduce_sum(float v) {
    #pragma unroll
    for (int o = 32; o > 0; o >>= 1) v += __shfl_xor(v, o);
    return v;
}

// packed two-value reductions over ONE HALF (256 threads) of a 512-thread block.
// sh must hold 16 floats. h = half index (threadIdx.x>>8). ALL 512 threads must call.
__device__ __forceinline__ float2 half_reduce_sum2(float2 v, float* sh, int h) {
    __syncthreads();
    #pragma unroll
    for (int o = 32; o > 0; o >>= 1) { v.x += __shfl_xor(v.x, o); v.y += __shfl_xor(v.y, o); }
    int w = threadIdx.x >> 6;                       // 0..7
    if ((threadIdx.x & 63) == 0) { sh[w*2] = v.x; sh[w*2+1] = v.y; }
    __syncthreads();
    int b0 = h * 8;
    return make_float2(sh[b0]+sh[b0+2]+sh[b0+4]+sh[b0+6],
                       sh[b0+1]+sh[b0+3]+sh[b0+5]+sh[b0+7]);
}

__device__ __forceinline__ float2 half_reduce_max2(float2 v, float* sh, int h) {
    __syncthreads();
    #pragma unroll
    for (int o = 32; o > 0; o >>= 1) {
        v.x = fmaxf(v.x, __shfl_xor(v.x, o));
        v.y = fmaxf(v.y, __shfl_xor(v.y, o));
    }
    int w = threadIdx.x >> 6;
    if ((threadIdx.x & 63) == 0) { sh[w*2] = v.x; sh[w*2+1] = v.y; }
    __syncthreads();
    int b0 = h * 8;
    return make_float2(fmaxf(fmaxf(sh[b0],sh[b0+2]), fmaxf(sh[b0+4],sh[b0+6])),
                       fmaxf(fmaxf(sh[b0+1],sh[b0+3]), fmaxf(sh[b0+5],sh[b0+7])));
}

// ---------------- dispatch 0: transpose dp_aff_w (WT1) + fa_aff_w (WT2) ----------------
__global__ void k_tr(const float* __restrict__ dp_aff_w, const float* __restrict__ fa_aff_w,
                     float* __restrict__ WT1, float* __restrict__ WT2) {
    __shared__ float tile[32][33];
    int tb = blockIdx.x;
    const float* S; float* D;
    if (tb < 64) { S = dp_aff_w; D = WT1; } else { S = fa_aff_w; D = WT2; tb -= 64; }
    int bx = tb & 7, by = tb >> 3;
    int tx = threadIdx.x & 31, ty = threadIdx.x >> 5;
    #pragma unroll
    for (int k = 0; k < 32; k += 8)
        tile[ty + k][tx] = S[(size_t)(by*32 + ty + k) * Cc + bx*32 + tx];
    __syncthreads();
    #pragma unroll
    for (int k = 0; k < 32; k += 8)
        D[(size_t)(bx*32 + ty + k) * Cc + by*32 + tx] = tile[tx][ty + k];
}

// ---------------- dispatch 1: 8-row GEMM blocks — nfT + M (norm branch), P (plain) ----------------
__global__ void k_pre(const float* __restrict__ lf, const float* __restrict__ dp_adj_w,
                      const float* __restrict__ WT1,
                      float* __restrict__ nfT, float* __restrict__ M, float* __restrict__ P) {
    __shared__ float sx[8][Cc];
    int bid = blockIdx.x;
    int t = threadIdx.x, lane = t & 63, wv = t >> 6;
    if (bid < RR/8) {
        int r0 = bid * 8;
        #pragma unroll
        for (int k = 0; k < 2; k++) {
            int r = 2*wv + k;
            float4 x = ((const float4*)(lf + (size_t)(r0 + r) * Cc))[lane];
            float ss = wave_reduce_sum(x.x*x.x + x.y*x.y + x.z*x.z + x.w*x.w);
            float inv = 1.f / fmaxf(sqrtf(ss), N_EPS);
            x.x *= inv; x.y *= inv; x.z *= inv; x.w *= inv;
            ((float4*)&sx[r][0])[lane] = x;
        }
        __syncthreads();
        int b = r0 / NN, i0 = r0 % NN;
        float4 cA, cB;
        cA.x = sx[0][t]; cA.y = sx[1][t]; cA.z = sx[2][t]; cA.w = sx[3][t];
        cB.x = sx[4][t]; cB.y = sx[5][t]; cB.z = sx[6][t]; cB.w = sx[7][t];
        float* np = nfT + (size_t)b * Cc * JP + (size_t)t * JP + i0;
        *((float4*)np) = cA;
        *((float4*)(np + 4)) = cB;
        float acc[8] = {0,0,0,0,0,0,0,0};
        #pragma unroll 4
        for (int c = 0; c < Cc; c++) {
            float w = dp_adj_w[(size_t)c * Cc + t];
            #pragma unroll
            for (int r = 0; r < 8; r++) acc[r] = fmaf(sx[r][c], w, acc[r]);
        }
        #pragma unroll
        for (int r = 0; r < 8; r++) M[(size_t)(r0 + r) * Cc + t] = acc[r];
    } else {
        int r0 = (bid - RR/8) * 8;
        #pragma unroll
        for (int k = 0; k < 2; k++) {
            int r = 2*wv + k;
            ((float4*)&sx[r][0])[lane] = ((const float4*)(lf + (size_t)(r0 + r) * Cc))[lane];
        }
        __syncthreads();
        float acc[8] = {0,0,0,0,0,0,0,0};
        #pragma unroll 4
        for (int c = 0; c < Cc; c++) {
            float w = WT1[(size_t)c * Cc + t];
            #pragma unroll
            for (int r = 0; r < 8; r++) acc[r] = fmaf(sx[r][c], w, acc[r]);
        }
        #pragma unroll
        for (int r = 0; r < 8; r++) P[(size_t)(r0 + r) * Cc + t] = acc[r];
    }
}

// ---------------- dispatch 2: fused diff_prop rows + stage-2 GEMVs (512 thr, 4 rows) ----------------
// Vectorized phases: all global loads float4; 4-row columns packed for b128 LDS broadcasts.
// Row ownership: half h owns rows (h, h+2).
__global__ void k_row1f(const float* __restrict__ nfT, const float* __restrict__ Min,
                        const float* __restrict__ P, const float* __restrict__ dp_aff_b,
                        const float* __restrict__ g, const float* __restrict__ bb,
                        const float* __restrict__ fa_adj_w, const float* __restrict__ WT2,
                        const float* __restrict__ fa_aff_b,
                        float* __restrict__ nfT2, float* __restrict__ M2,
                        float* __restrict__ lf2) {
    __shared__ __align__(16) float smT[Cc*4];    // M rows packed [c][r]
    __shared__ __align__(16) float saraw[4*NN];  // raw A rows [r][j]
    __shared__ __align__(16) float saT[NN*4];    // normalized A packed [j][r]
    __shared__ __align__(16) float suT[Cc*4];    // x1 rows packed [c][r]
    __shared__ __align__(16) float buf[8192];    // 32KB partial-combine union
    __shared__ float sh[16];
    __shared__ float sinv[4];
    int t = threadIdx.x, h = t >> 8, tt = t & 255;
    int b = blockIdx.x & 7;
    int i0 = (blockIdx.x >> 3) * 4;
    size_t base = (size_t)b * NN * Cc;
    {   // pack 4 M rows transposed: smT[c*4+r] = M[i0+r][c]
        const float* src = Min + base + (size_t)i0 * Cc;
        #pragma unroll
        for (int o = t; o < 1024; o += 512) {
            int c = o >> 2, r = o & 3;
            smT[o] = src[(size_t)r * Cc + c];
        }
    }
    __syncthreads();
    // ---- phase A: A[r][j] = sum_c smT[c][r] * nfT[c][j], float4 over j ----
    {
        int q = t & 63, cid = t >> 6;            // j-quad, c-chunk(32)
        if (q < 50) {
            int c0 = cid * 32;
            const float* nfp = nfT + (size_t)b * Cc * JP + (size_t)c0 * JP + 4*q;
            float4 z4 = make_float4(0.f,0.f,0.f,0.f);
            float4 a0 = z4, a1 = z4, a2 = z4, a3 = z4;
            #pragma unroll 8
            for (int c = 0; c < 32; c++) {
                float4 v  = *(const float4*)(nfp + (size_t)c * JP);
                float4 mv = *(const float4*)(&smT[(c0 + c) * 4]);
                FMA4(a0, mv.x, v); FMA4(a1, mv.y, v);
                FMA4(a2, mv.z, v); FMA4(a3, mv.w, v);
            }
            float* pp = buf + cid * 800 + 4*q;   // [cid][r][j]
            *(float4*)(pp      ) = a0;
            *(float4*)(pp + 200) = a1;
            *(float4*)(pp + 400) = a2;
            *(float4*)(pp + 600) = a3;
        }
    }
    __syncthreads();
    for (int o = t; o < 800; o += 512) {         // combine 8 c-chunk partials
        float s = 0.f;
        #pragma unroll
        for (int p = 0; p < 8; p++) s += buf[p*800 + o];
        saraw[o] = s;
    }
    __syncthreads();
    // ---- phase B: exp(5*(a-max)), zero diag, L1 norm; s = sum/max(sum,eps) ----
    int lr0 = h, lr1 = h + 2;
    float2 vm;
    vm.x = (tt < NN) ? saraw[lr0*NN + tt] : -INFINITY;
    vm.y = (tt < NN) ? saraw[lr1*NN + tt] : -INFINITY;
    float2 m = half_reduce_max2(vm, sh, h);
    float e0 = (tt < NN && tt != i0 + lr0) ? expf(SCALE * (vm.x - m.x)) : 0.f;
    float e1 = (tt < NN && tt != i0 + lr1) ? expf(SCALE * (vm.y - m.y)) : 0.f;
    float2 sum = half_reduce_sum2(make_float2(e0, e1), sh, h);
    if (tt < NN) {
        saT[tt*4 + lr0] = e0 / fmaxf(sum.x, N_EPS);
        saT[tt*4 + lr1] = e1 / fmaxf(sum.y, N_EPS);
    }
    float s0 = sum.x / fmaxf(sum.x, N_EPS);
    float s1 = sum.y / fmaxf(sum.y, N_EPS);
    __syncthreads();
    // ---- phase C: U[r][cc] = sum_j saT[j][r] * P[j][cc], float4 over cc ----
    const float* Pb = P + base;
    {
        int qc = t & 63, jc = t >> 6;            // col-quad, j-chunk(25)
        int j0 = jc * 25;
        float4 z4 = make_float4(0.f,0.f,0.f,0.f);
        float4 u0 = z4, u1 = z4, u2 = z4, u3 = z4;
        #pragma unroll 5
        for (int j = j0; j < j0 + 25; j++) {
            float4 pv = *(const float4*)(Pb + (size_t)j * Cc + 4*qc);
            float4 av = *(const float4*)(&saT[j*4]);
            FMA4(u0, av.x, pv); FMA4(u1, av.y, pv);
            FMA4(u2, av.z, pv); FMA4(u3, av.w, pv);
        }
        float* pp = buf + jc*1024 + 4*qc;        // [jc][r][cc]
        *(float4*)(pp      ) = u0;
        *(float4*)(pp + 256) = u1;
        *(float4*)(pp + 512) = u2;
        *(float4*)(pp + 768) = u3;
    }
    __syncthreads();
    float acc0 = 0.f, acc1 = 0.f;                // outputs (lr0,tt)=buf idx t, (lr1,tt)=t+512
    #pragma unroll
    for (int p = 0; p < 8; p++) { acc0 += buf[p*1024 + t]; acc1 += buf[p*1024 + t + 512]; }
    float bv = dp_aff_b[tt];
    float y0 = fmaf(s0, Pb[(size_t)(i0 + lr0) * Cc + tt] + bv, -acc0);
    float y1 = fmaf(s1, Pb[(size_t)(i0 + lr1) * Cc + tt] + bv, -acc1);
    // ---- LayerNorm + LeakyReLU -> x1 (LDS only) ----
    float gg = g[tt], bbv = bb[tt];
    float2 mean2 = half_reduce_sum2(make_float2(y0, y1), sh, h);
    float d0 = y0 - mean2.x * (1.f/256.f);
    float d1 = y1 - mean2.y * (1.f/256.f);
    float2 var2 = half_reduce_sum2(make_float2(d0*d0, d1*d1), sh, h);
    float z0 = d0 / sqrtf(var2.x * (1.f/256.f) + LN_EPS) * gg + bbv;
    float z1 = d1 / sqrtf(var2.y * (1.f/256.f) + LN_EPS) * gg + bbv;
    z0 = (z0 >= 0.f) ? z0 : SLOPE * z0;
    z1 = (z1 >= 0.f) ? z1 : SLOPE * z1;
    suT[tt*4 + lr0] = z0; suT[tt*4 + lr1] = z1;
    float2 ss2 = half_reduce_sum2(make_float2(z0*z0, z1*z1), sh, h);
    if (tt == 0) {
        sinv[lr0] = 1.f / fmaxf(sqrtf(ss2.x), N_EPS);
        sinv[lr1] = 1.f / fmaxf(sqrtf(ss2.y), N_EPS);
    }
    __syncthreads();
    // nf2 transposed write (half 0): float4 over the 4 rows
    if (h == 0) {
        float4 col;
        col.x = suT[tt*4+0] * sinv[0]; col.y = suT[tt*4+1] * sinv[1];
        col.z = suT[tt*4+2] * sinv[2]; col.w = suT[tt*4+3] * sinv[3];
        *((float4*)(nfT2 + (size_t)b * Cc * JP + (size_t)tt * JP + i0)) = col;
    }
    // ---- phase D: both stage-2 GEMVs, float4 weight loads ----
    {
        int qc = t & 63, gidx = t >> 6;
        int mt = gidx & 1, cch = gidx >> 1;      // matrix, c-chunk(64)
        const float* Wm = mt ? WT2 : fa_adj_w;
        int c0 = cch * 64;
        float4 z4 = make_float4(0.f,0.f,0.f,0.f);
        float4 d0v = z4, d1v = z4, d2v = z4, d3v = z4;
        #pragma unroll 8
        for (int c = c0; c < c0 + 64; c++) {
            float4 wv = *(const float4*)(Wm + (size_t)c * Cc + 4*qc);
            float4 uv = *(const float4*)(&suT[c*4]);
            FMA4(d0v, uv.x, wv); FMA4(d1v, uv.y, wv);
            FMA4(d2v, uv.z, wv); FMA4(d3v, uv.w, wv);
        }
        float* pp = buf + cch*2048 + mt*1024 + 4*qc;   // [cch][mt][r][cc]
        *(float4*)(pp      ) = d0v;
        *(float4*)(pp + 256) = d1v;
        *(float4*)(pp + 512) = d2v;
        *(float4*)(pp + 768) = d3v;
    }
    __syncthreads();
    #pragma unroll
    for (int k = 0; k < 4; k++) {
        int o = t + k*512;
        int mt2 = o >> 10, r2 = (o >> 8) & 3, cc2 = o & 255;
        float sv = buf[o] + buf[o+2048] + buf[o+4096] + buf[o+6144];
        if (mt2 == 0) M2 [base + (size_t)(i0+r2)*Cc + cc2] = sv * sinv[r2];
        else          lf2[base + (size_t)(i0+r2)*Cc + cc2] = sv + fa_aff_b[cc2];
    }
}

// ---------------- dispatch 3: feat_aggr rows (512 thr, 4 rows), vectorized ----------------
__global__ void k_row2f(const float* __restrict__ nfT2, const float* __restrict__ M2,
                        const float* __restrict__ lf2, const float* __restrict__ g,
                        const float* __restrict__ bb, float* __restrict__ x2,
                        float* __restrict__ nf3) {
    __shared__ __align__(16) float smT[Cc*4];
    __shared__ __align__(16) float saraw[4*NN];
    __shared__ __align__(16) float saT[NN*4];
    __shared__ __align__(16) float buf[8192];
    __shared__ float sh[16];
    int t = threadIdx.x, h = t >> 8, tt = t & 255;
    int b = blockIdx.x & 7;
    int i0 = (blockIdx.x >> 3) * 4;
    size_t base = (size_t)b * NN * Cc;
    {
        const float* src = M2 + base + (size_t)i0 * Cc;
        #pragma unroll
        for (int o = t; o < 1024; o += 512) {
            int c = o >> 2, r = o & 3;
            smT[o] = src[(size_t)r * Cc + c];
        }
    }
    __syncthreads();
    // phase A
    {
        int q = t & 63, cid = t >> 6;
        if (q < 50) {
            int c0 = cid * 32;
            const float* nfp = nfT2 + (size_t)b * Cc * JP + (size_t)c0 * JP + 4*q;
            float4 z4 = make_float4(0.f,0.f,0.f,0.f);
            float4 a0 = z4, a1 = z4, a2 = z4, a3 = z4;
            #pragma unroll 8
            for (int c = 0; c < 32; c++) {
                float4 v  = *(const float4*)(nfp + (size_t)c * JP);
                float4 mv = *(const float4*)(&smT[(c0 + c) * 4]);
                FMA4(a0, mv.x, v); FMA4(a1, mv.y, v);
                FMA4(a2, mv.z, v); FMA4(a3, mv.w, v);
            }
            float* pp = buf + cid * 800 + 4*q;
            *(float4*)(pp      ) = a0;
            *(float4*)(pp + 200) = a1;
            *(float4*)(pp + 400) = a2;
            *(float4*)(pp + 600) = a3;
        }
    }
    __syncthreads();
    for (int o = t; o < 800; o += 512) {
        float s = 0.f;
        #pragma unroll
        for (int p = 0; p < 8; p++) s += buf[p*800 + o];
        saraw[o] = s;
    }
    __syncthreads();
    // softmax rows (h, h+2)
    int lr0 = h, lr1 = h + 2;
    float2 vm;
    vm.x = (tt < NN) ? saraw[lr0*NN + tt] : -INFINITY;
    vm.y = (tt < NN) ? saraw[lr1*NN + tt] : -INFINITY;
    float2 m = half_reduce_max2(vm, sh, h);
    float e0 = (tt < NN) ? expf(SCALE * (vm.x - m.x)) : 0.f;
    float e1 = (tt < NN) ? expf(SCALE * (vm.y - m.y)) : 0.f;
    float2 sum = half_reduce_sum2(make_float2(e0, e1), sh, h);
    if (tt < NN) { saT[tt*4 + lr0] = e0 / sum.x; saT[tt*4 + lr1] = e1 / sum.y; }
    __syncthreads();
    // phase C: y = A @ lf2
    const float* l2b = lf2 + base;
    {
        int qc = t & 63, jc = t >> 6;
        int j0 = jc * 25;
        float4 z4 = make_float4(0.f,0.f,0.f,0.f);
        float4 u0 = z4, u1 = z4, u2 = z4, u3 = z4;
        #pragma unroll 5
        for (int j = j0; j < j0 + 25; j++) {
            float4 pv = *(const float4*)(l2b + (size_t)j * Cc + 4*qc);
            float4 av = *(const float4*)(&saT[j*4]);
            FMA4(u0, av.x, pv); FMA4(u1, av.y, pv);
            FMA4(u2, av.z, pv); FMA4(u3, av.w, pv);
        }
        float* pp = buf + jc*1024 + 4*qc;
        *(float4*)(pp      ) = u0;
        *(float4*)(pp + 256) = u1;
        *(float4*)(pp + 512) = u2;
        *(float4*)(pp + 768) = u3;
    }
    __syncthreads();
    float y0 = 0.f, y1 = 0.f;
    #pragma unroll
    for (int p = 0; p < 8; p++) { y0 += buf[p*1024 + t]; y1 += buf[p*1024 + t + 512]; }
    // LN + leaky + l2norm epilogue
    float gg = g[tt], bbv = bb[tt];
    float2 mean2 = half_reduce_sum2(make_float2(y0, y1), sh, h);
    float d0 = y0 - mean2.x * (1.f/256.f);
    float d1 = y1 - mean2.y * (1.f/256.f);
    float2 var2 = half_reduce_sum2(make_float2(d0*d0, d1*d1), sh, h);
    float z0 = d0 / sqrtf(var2.x * (1.f/256.f) + LN_EPS) * gg + bbv;
    float z1 = d1 / sqrtf(var2.y * (1.f/256.f) + LN_EPS) * gg + bbv;
    z0 = (z0 >= 0.f) ? z0 : SLOPE * z0;
    z1 = (z1 >= 0.f) ? z1 : SLOPE * z1;
    x2[base + (size_t)(i0 + lr0) * Cc + tt] = z0;
    x2[base + (size_t)(i0 + lr1) * Cc + tt] = z1;
    float2 ss2 = half_reduce_sum2(make_float2(z0*z0, z1*z1), sh, h);
    nf3[base + (size_t)(i0 + lr0) * Cc + tt] = z0 / fmaxf(sqrtf(ss2.x), N_EPS);
    nf3[base + (size_t)(i0 + lr1) * Cc + tt] = z1 / fmaxf(sqrtf(ss2.y), N_EPS);
}

// ---------------- dispatch 4: fused wsum + node_att (4 rows/block, 256 thr) ----------------
__global__ void k_natt(const float* __restrict__ x2, const float* __restrict__ nf3,
                       const float* __restrict__ pos, const float* __restrict__ w,
                       const float* __restrict__ nb, float* __restrict__ out) {
    __shared__ float svb[4][Cc];
    int t = threadIdx.x, lane = t & 63, wv = t >> 6;
    int b = blockIdx.x & 7;
    int i = (blockIdx.x >> 3) * 4 + wv;
    const float4* slab = (const float4*)(nf3 + (size_t)b * NN * Cc);
    float4 acc = make_float4(0.f, 0.f, 0.f, 0.f);
    for (int j = wv * 50; j < wv * 50 + 50; j++) {
        float4 q = slab[j * 64 + lane];
        float wj = w[j];
        acc.x = fmaf(wj, q.x, acc.x);
        acc.y = fmaf(wj, q.y, acc.y);
        acc.z = fmaf(wj, q.z, acc.z);
        acc.w = fmaf(wj, q.w, acc.w);
    }
    ((float4*)&svb[wv][0])[lane] = acc;
    __syncthreads();
    float4 p0 = ((const float4*)&svb[0][0])[lane];
    float4 p1 = ((const float4*)&svb[1][0])[lane];
    float4 p2 = ((const float4*)&svb[2][0])[lane];
    float4 p3 = ((const float4*)&svb[3][0])[lane];
    float4 vb;
    vb.x = (p0.x + p1.x) + (p2.x + p3.x);
    vb.y = (p0.y + p1.y) + (p2.y + p3.y);
    vb.z = (p0.z + p1.z) + (p2.z + p3.z);
    vb.w = (p0.w + p1.w) + (p2.w + p3.w);
    size_t bi = (size_t)b * NN + i;
    float4 nv = ((const float4*)(nf3 + bi * Cc))[lane];
    float val = nv.x*vb.x + nv.y*vb.y + nv.z*vb.z + nv.w*vb.w;
    if (lane < 9) val += pos[bi * 9 + lane] * w[NN + lane];
    val = wave_reduce_sum(val);
    float att = 1.f / (1.f + expf(-(val + nb[0])));
    float4 xo = ((const float4*)(x2 + bi * Cc))[lane];
    xo.x *= att; xo.y *= att; xo.z *= att; xo.w *= att;
    ((float4*)(out + bi * Cc))[lane] = xo;
}

// ---------------- launcher ----------------
extern "C" void kernel_launch(void* const* d_in, const int* in_sizes, int n_in,
                              void* d_out, int out_size, void* d_ws, size_t ws_size,
                              hipStream_t stream) {
    (void)in_sizes; (void)n_in; (void)out_size; (void)ws_size;
    const float* lf       = (const float*)d_in[0];
    const float* pos      = (const float*)d_in[2];
    const float* dp_adj_w = (const float*)d_in[3];
    const float* dp_aff_w = (const float*)d_in[4];
    const float* dp_aff_b = (const float*)d_in[5];
    const float* dp_ln_g  = (const float*)d_in[6];
    const float* dp_ln_b  = (const float*)d_in[7];
    const float* fa_adj_w = (const float*)d_in[8];
    const float* fa_aff_w = (const float*)d_in[9];
    const float* fa_aff_b = (const float*)d_in[10];
    const float* fa_ln_g  = (const float*)d_in[11];
    const float* fa_ln_b  = (const float*)d_in[12];
    const float* na_w     = (const float*)d_in[13];
    const float* na_b     = (const float*)d_in[14];
    float* out = (float*)d_out;
    float* ws  = (float*)d_ws;

    float* nfT  = ws;                    // Bn*Cc*JP
    float* nfT2 = nfT  + Bn * Cc * JP;   // Bn*Cc*JP
    float* M    = nfT2 + Bn * Cc * JP;   // RR*Cc  (M2 written in-place)
    float* P    = M    + RR * Cc;        // RR*Cc
    float* lf2  = P    + RR * Cc;        // RR*Cc
    float* x2   = lf2  + RR * Cc;        // RR*Cc
    float* nf3  = x2   + RR * Cc;        // RR*Cc
    float* WT1  = nf3  + RR * Cc;        // Cc*Cc
    float* WT2  = WT1  + Cc * Cc;        // Cc*Cc

    k_tr   <<<128,        dim3(256), 0, stream>>>(dp_aff_w, fa_aff_w, WT1, WT2);
    k_pre  <<<RR/8 * 2,   dim3(256), 0, stream>>>(lf, dp_adj_w, WT1, nfT, M, P);
    k_row1f<<<Bn * NN/4,  dim3(512), 0, stream>>>(nfT, M, P, dp_aff_b, dp_ln_g, dp_ln_b,
                                                  fa_adj_w, WT2, fa_aff_b, nfT2, M, lf2);
    k_row2f<<<Bn * NN/4,  dim3(512), 0, stream>>>(nfT2, M, lf2, fa_ln_g, fa_ln_b, x2, nf3);
    k_natt <<<Bn * NN/4,  dim3(256), 0, stream>>>(x2, nf3, pos, na_w, na_b, out);
}

// Round 9
// 64.204 us; speedup vs baseline: 1.7432x; 1.0997x over previous
//
#include <hip/hip_runtime.h>
#include <math.h>

#define Bn 8
#define NN 200
#define Cc 256
#define RR (Bn*NN)       // 1600 rows total
#define JP 200           // j-stride of transposed nf
#define N_EPS 1e-12f
#define LN_EPS 1e-5f
#define SLOPE 0.01f
#define SCALE 5.0f

#define FMA4(acc, s, v) { acc.x = fmaf((s), (v).x, acc.x); acc.y = fmaf((s), (v).y, acc.y); \
                          acc.z = fmaf((s), (v).z, acc.z); acc.w = fmaf((s), (v).w, acc.w); }

// ---------------- reduction helpers ----------------
__device__ __forceinline__ float wave_reduce_sum(float v) {
    #pragma unroll
    for (int o = 32; o > 0; o >>= 1) v += __shfl_xor(v, o);
    return v;
}

// packed two-value reductions over ONE HALF (256 threads) of a 512-thread block.
// sh must hold 16 floats. h = half index (threadIdx.x>>8). ALL 512 threads must call.
__device__ __forceinline__ float2 half_reduce_sum2(float2 v, float* sh, int h) {
    __syncthreads();
    #pragma unroll
    for (int o = 32; o > 0; o >>= 1) { v.x += __shfl_xor(v.x, o); v.y += __shfl_xor(v.y, o); }
    int w = threadIdx.x >> 6;                       // 0..7
    if ((threadIdx.x & 63) == 0) { sh[w*2] = v.x; sh[w*2+1] = v.y; }
    __syncthreads();
    int b0 = h * 8;
    return make_float2(sh[b0]+sh[b0+2]+sh[b0+4]+sh[b0+6],
                       sh[b0+1]+sh[b0+3]+sh[b0+5]+sh[b0+7]);
}

__device__ __forceinline__ float2 half_reduce_max2(float2 v, float* sh, int h) {
    __syncthreads();
    #pragma unroll
    for (int o = 32; o > 0; o >>= 1) {
        v.x = fmaxf(v.x, __shfl_xor(v.x, o));
        v.y = fmaxf(v.y, __shfl_xor(v.y, o));
    }
    int w = threadIdx.x >> 6;
    if ((threadIdx.x & 63) == 0) { sh[w*2] = v.x; sh[w*2+1] = v.y; }
    __syncthreads();
    int b0 = h * 8;
    return make_float2(fmaxf(fmaxf(sh[b0],sh[b0+2]), fmaxf(sh[b0+4],sh[b0+6])),
                       fmaxf(fmaxf(sh[b0+1],sh[b0+3]), fmaxf(sh[b0+5],sh[b0+7])));
}

// ---------------- dispatch 0: transpose dp_aff_w (WT1) + fa_aff_w (WT2) ----------------
__global__ void k_tr(const float* __restrict__ dp_aff_w, const float* __restrict__ fa_aff_w,
                     float* __restrict__ WT1, float* __restrict__ WT2) {
    __shared__ float tile[32][33];
    int tb = blockIdx.x;
    const float* S; float* D;
    if (tb < 64) { S = dp_aff_w; D = WT1; } else { S = fa_aff_w; D = WT2; tb -= 64; }
    int bx = tb & 7, by = tb >> 3;
    int tx = threadIdx.x & 31, ty = threadIdx.x >> 5;
    #pragma unroll
    for (int k = 0; k < 32; k += 8)
        tile[ty + k][tx] = S[(size_t)(by*32 + ty + k) * Cc + bx*32 + tx];
    __syncthreads();
    #pragma unroll
    for (int k = 0; k < 32; k += 8)
        D[(size_t)(bx*32 + ty + k) * Cc + by*32 + tx] = tile[tx][ty + k];
}

// ---------------- dispatch 1: 8-row GEMM blocks, vectorized weight loads ----------------
// norm branch (bid < RR/8): nfT + M = l2norm(lf)@dp_adj_w; else P = lf@WT1.
__global__ void k_pre(const float* __restrict__ lf, const float* __restrict__ dp_adj_w,
                      const float* __restrict__ WT1,
                      float* __restrict__ nfT, float* __restrict__ M, float* __restrict__ P) {
    __shared__ __align__(16) float sx[8][Cc];    // 8 KB input rows
    __shared__ __align__(16) float buf[8192];    // 32 KB partials [cid][r][qc] float4
    int bid = blockIdx.x;
    int t = threadIdx.x, lane = t & 63, wvi = t >> 6;
    bool nb = bid < RR/8;
    int r0 = (nb ? bid : bid - RR/8) * 8;
    const float* W = nb ? dp_adj_w : WT1;
    #pragma unroll
    for (int k = 0; k < 2; k++) {
        int r = 2*wvi + k;
        float4 x = ((const float4*)(lf + (size_t)(r0 + r) * Cc))[lane];
        if (nb) {
            float ss = wave_reduce_sum(x.x*x.x + x.y*x.y + x.z*x.z + x.w*x.w);
            float inv = 1.f / fmaxf(sqrtf(ss), N_EPS);
            x.x *= inv; x.y *= inv; x.z *= inv; x.w *= inv;
        }
        ((float4*)&sx[r][0])[lane] = x;
    }
    __syncthreads();
    if (nb) {   // transposed nfT write: column t, 8 consecutive j's
        int b = r0 / NN, i0 = r0 % NN;
        float4 cA, cB;
        cA.x = sx[0][t]; cA.y = sx[1][t]; cA.z = sx[2][t]; cA.w = sx[3][t];
        cB.x = sx[4][t]; cB.y = sx[5][t]; cB.z = sx[6][t]; cB.w = sx[7][t];
        float* np = nfT + (size_t)b * Cc * JP + (size_t)t * JP + i0;
        *((float4*)np) = cA;
        *((float4*)(np + 4)) = cB;
    }
    // GEMM: thread (qc = t&63 col-quad, cid = t>>6 c-chunk of 64), float4 weights
    {
        int qc = t & 63, cid = t >> 6;
        int c0 = cid * 64;
        float4 z = make_float4(0.f,0.f,0.f,0.f);
        float4 acc0=z, acc1=z, acc2=z, acc3=z, acc4=z, acc5=z, acc6=z, acc7=z;
        #pragma unroll 4
        for (int c4 = c0; c4 < c0 + 64; c4 += 4) {
            float4 w0 = *(const float4*)(W + (size_t)(c4+0) * Cc + 4*qc);
            float4 w1 = *(const float4*)(W + (size_t)(c4+1) * Cc + 4*qc);
            float4 w2 = *(const float4*)(W + (size_t)(c4+2) * Cc + 4*qc);
            float4 w3 = *(const float4*)(W + (size_t)(c4+3) * Cc + 4*qc);
            float4 xr;
            xr = *(const float4*)(&sx[0][c4]);
            FMA4(acc0, xr.x, w0); FMA4(acc0, xr.y, w1); FMA4(acc0, xr.z, w2); FMA4(acc0, xr.w, w3);
            xr = *(const float4*)(&sx[1][c4]);
            FMA4(acc1, xr.x, w0); FMA4(acc1, xr.y, w1); FMA4(acc1, xr.z, w2); FMA4(acc1, xr.w, w3);
            xr = *(const float4*)(&sx[2][c4]);
            FMA4(acc2, xr.x, w0); FMA4(acc2, xr.y, w1); FMA4(acc2, xr.z, w2); FMA4(acc2, xr.w, w3);
            xr = *(const float4*)(&sx[3][c4]);
            FMA4(acc3, xr.x, w0); FMA4(acc3, xr.y, w1); FMA4(acc3, xr.z, w2); FMA4(acc3, xr.w, w3);
            xr = *(const float4*)(&sx[4][c4]);
            FMA4(acc4, xr.x, w0); FMA4(acc4, xr.y, w1); FMA4(acc4, xr.z, w2); FMA4(acc4, xr.w, w3);
            xr = *(const float4*)(&sx[5][c4]);
            FMA4(acc5, xr.x, w0); FMA4(acc5, xr.y, w1); FMA4(acc5, xr.z, w2); FMA4(acc5, xr.w, w3);
            xr = *(const float4*)(&sx[6][c4]);
            FMA4(acc6, xr.x, w0); FMA4(acc6, xr.y, w1); FMA4(acc6, xr.z, w2); FMA4(acc6, xr.w, w3);
            xr = *(const float4*)(&sx[7][c4]);
            FMA4(acc7, xr.x, w0); FMA4(acc7, xr.y, w1); FMA4(acc7, xr.z, w2); FMA4(acc7, xr.w, w3);
        }
        float4* b4 = (float4*)buf;
        int o = cid * 512 + qc;
        b4[o      ] = acc0; b4[o +  64] = acc1; b4[o + 128] = acc2; b4[o + 192] = acc3;
        b4[o + 256] = acc4; b4[o + 320] = acc5; b4[o + 384] = acc6; b4[o + 448] = acc7;
    }
    __syncthreads();
    {   // combine 4 c-chunk partials, float4 writes
        float4* b4 = (float4*)buf;
        float* Y = nb ? M : P;
        #pragma unroll
        for (int k = 0; k < 2; k++) {
            int o4 = t + k*256;                  // [0,512): r = o4>>6, qc = o4&63
            int r = o4 >> 6, qc = o4 & 63;
            float4 s0 = b4[o4], s1 = b4[512 + o4], s2 = b4[1024 + o4], s3 = b4[1536 + o4];
            float4 sv;
            sv.x = (s0.x + s1.x) + (s2.x + s3.x);
            sv.y = (s0.y + s1.y) + (s2.y + s3.y);
            sv.z = (s0.z + s1.z) + (s2.z + s3.z);
            sv.w = (s0.w + s1.w) + (s2.w + s3.w);
            *(float4*)(Y + (size_t)(r0 + r) * Cc + 4*qc) = sv;
        }
    }
}

// ---------------- dispatch 2: fused diff_prop rows + stage-2 GEMVs (512 thr, 4 rows) ----------------
// Row ownership: half h owns rows (h, h+2).
__global__ void k_row1f(const float* __restrict__ nfT, const float* __restrict__ Min,
                        const float* __restrict__ P, const float* __restrict__ dp_aff_b,
                        const float* __restrict__ g, const float* __restrict__ bb,
                        const float* __restrict__ fa_adj_w, const float* __restrict__ WT2,
                        const float* __restrict__ fa_aff_b,
                        float* __restrict__ nfT2, float* __restrict__ M2,
                        float* __restrict__ lf2) {
    __shared__ __align__(16) float smT[Cc*4];    // M rows packed [c][r]
    __shared__ __align__(16) float saraw[4*NN];  // raw A rows [r][j]
    __shared__ __align__(16) float saT[NN*4];    // normalized A packed [j][r]
    __shared__ __align__(16) float suT[Cc*4];    // x1 rows packed [c][r]
    __shared__ __align__(16) float buf[8192];    // 32KB partial-combine union
    __shared__ float sh[16];
    __shared__ float sinv[4];
    int t = threadIdx.x, h = t >> 8, tt = t & 255;
    int b = blockIdx.x & 7;
    int i0 = (blockIdx.x >> 3) * 4;
    size_t base = (size_t)b * NN * Cc;
    {   // pack 4 M rows transposed: smT[c*4+r] = M[i0+r][c]
        const float* src = Min + base + (size_t)i0 * Cc;
        #pragma unroll
        for (int o = t; o < 1024; o += 512) {
            int c = o >> 2, r = o & 3;
            smT[o] = src[(size_t)r * Cc + c];
        }
    }
    __syncthreads();
    // ---- phase A: A[r][j] = sum_c smT[c][r] * nfT[c][j], float4 over j ----
    {
        int q = t & 63, cid = t >> 6;            // j-quad, c-chunk(32)
        if (q < 50) {
            int c0 = cid * 32;
            const float* nfp = nfT + (size_t)b * Cc * JP + (size_t)c0 * JP + 4*q;
            float4 z4 = make_float4(0.f,0.f,0.f,0.f);
            float4 a0 = z4, a1 = z4, a2 = z4, a3 = z4;
            #pragma unroll 8
            for (int c = 0; c < 32; c++) {
                float4 v  = *(const float4*)(nfp + (size_t)c * JP);
                float4 mv = *(const float4*)(&smT[(c0 + c) * 4]);
                FMA4(a0, mv.x, v); FMA4(a1, mv.y, v);
                FMA4(a2, mv.z, v); FMA4(a3, mv.w, v);
            }
            float* pp = buf + cid * 800 + 4*q;   // [cid][r][j]
            *(float4*)(pp      ) = a0;
            *(float4*)(pp + 200) = a1;
            *(float4*)(pp + 400) = a2;
            *(float4*)(pp + 600) = a3;
        }
    }
    __syncthreads();
    for (int o = t; o < 800; o += 512) {         // combine 8 c-chunk partials
        float s = 0.f;
        #pragma unroll
        for (int p = 0; p < 8; p++) s += buf[p*800 + o];
        saraw[o] = s;
    }
    __syncthreads();
    // ---- phase B: exp(5*(a-max)), zero diag, L1 norm; s = sum/max(sum,eps) ----
    int lr0 = h, lr1 = h + 2;
    float2 vm;
    vm.x = (tt < NN) ? saraw[lr0*NN + tt] : -INFINITY;
    vm.y = (tt < NN) ? saraw[lr1*NN + tt] : -INFINITY;
    float2 m = half_reduce_max2(vm, sh, h);
    float e0 = (tt < NN && tt != i0 + lr0) ? expf(SCALE * (vm.x - m.x)) : 0.f;
    float e1 = (tt < NN && tt != i0 + lr1) ? expf(SCALE * (vm.y - m.y)) : 0.f;
    float2 sum = half_reduce_sum2(make_float2(e0, e1), sh, h);
    if (tt < NN) {
        saT[tt*4 + lr0] = e0 / fmaxf(sum.x, N_EPS);
        saT[tt*4 + lr1] = e1 / fmaxf(sum.y, N_EPS);
    }
    float s0 = sum.x / fmaxf(sum.x, N_EPS);
    float s1 = sum.y / fmaxf(sum.y, N_EPS);
    __syncthreads();
    // ---- phase C: U[r][cc] = sum_j saT[j][r] * P[j][cc], float4 over cc ----
    const float* Pb = P + base;
    {
        int qc = t & 63, jc = t >> 6;            // col-quad, j-chunk(25)
        int j0 = jc * 25;
        float4 z4 = make_float4(0.f,0.f,0.f,0.f);
        float4 u0 = z4, u1 = z4, u2 = z4, u3 = z4;
        #pragma unroll 5
        for (int j = j0; j < j0 + 25; j++) {
            float4 pv = *(const float4*)(Pb + (size_t)j * Cc + 4*qc);
            float4 av = *(const float4*)(&saT[j*4]);
            FMA4(u0, av.x, pv); FMA4(u1, av.y, pv);
            FMA4(u2, av.z, pv); FMA4(u3, av.w, pv);
        }
        float* pp = buf + jc*1024 + 4*qc;        // [jc][r][cc]
        *(float4*)(pp      ) = u0;
        *(float4*)(pp + 256) = u1;
        *(float4*)(pp + 512) = u2;
        *(float4*)(pp + 768) = u3;
    }
    __syncthreads();
    float acc0 = 0.f, acc1 = 0.f;                // outputs (lr0,tt)=buf idx t, (lr1,tt)=t+512
    #pragma unroll
    for (int p = 0; p < 8; p++) { acc0 += buf[p*1024 + t]; acc1 += buf[p*1024 + t + 512]; }
    float bv = dp_aff_b[tt];
    float y0 = fmaf(s0, Pb[(size_t)(i0 + lr0) * Cc + tt] + bv, -acc0);
    float y1 = fmaf(s1, Pb[(size_t)(i0 + lr1) * Cc + tt] + bv, -acc1);
    // ---- LayerNorm + LeakyReLU -> x1 (LDS only) ----
    float gg = g[tt], bbv = bb[tt];
    float2 mean2 = half_reduce_sum2(make_float2(y0, y1), sh, h);
    float d0 = y0 - mean2.x * (1.f/256.f);
    float d1 = y1 - mean2.y * (1.f/256.f);
    float2 var2 = half_reduce_sum2(make_float2(d0*d0, d1*d1), sh, h);
    float z0 = d0 / sqrtf(var2.x * (1.f/256.f) + LN_EPS) * gg + bbv;
    float z1 = d1 / sqrtf(var2.y * (1.f/256.f) + LN_EPS) * gg + bbv;
    z0 = (z0 >= 0.f) ? z0 : SLOPE * z0;
    z1 = (z1 >= 0.f) ? z1 : SLOPE * z1;
    suT[tt*4 + lr0] = z0; suT[tt*4 + lr1] = z1;
    float2 ss2 = half_reduce_sum2(make_float2(z0*z0, z1*z1), sh, h);
    if (tt == 0) {
        sinv[lr0] = 1.f / fmaxf(sqrtf(ss2.x), N_EPS);
        sinv[lr1] = 1.f / fmaxf(sqrtf(ss2.y), N_EPS);
    }
    __syncthreads();
    // nf2 transposed write (half 0): float4 over the 4 rows
    if (h == 0) {
        float4 col;
        col.x = suT[tt*4+0] * sinv[0]; col.y = suT[tt*4+1] * sinv[1];
        col.z = suT[tt*4+2] * sinv[2]; col.w = suT[tt*4+3] * sinv[3];
        *((float4*)(nfT2 + (size_t)b * Cc * JP + (size_t)tt * JP + i0)) = col;
    }
    // ---- phase D: both stage-2 GEMVs, float4 weight loads ----
    {
        int qc = t & 63, gidx = t >> 6;
        int mt = gidx & 1, cch = gidx >> 1;      // matrix, c-chunk(64)
        const float* Wm = mt ? WT2 : fa_adj_w;
        int c0 = cch * 64;
        float4 z4 = make_float4(0.f,0.f,0.f,0.f);
        float4 d0v = z4, d1v = z4, d2v = z4, d3v = z4;
        #pragma unroll 8
        for (int c = c0; c < c0 + 64; c++) {
            float4 wv = *(const float4*)(Wm + (size_t)c * Cc + 4*qc);
            float4 uv = *(const float4*)(&suT[c*4]);
            FMA4(d0v, uv.x, wv); FMA4(d1v, uv.y, wv);
            FMA4(d2v, uv.z, wv); FMA4(d3v, uv.w, wv);
        }
        float* pp = buf + cch*2048 + mt*1024 + 4*qc;   // [cch][mt][r][cc]
        *(float4*)(pp      ) = d0v;
        *(float4*)(pp + 256) = d1v;
        *(float4*)(pp + 512) = d2v;
        *(float4*)(pp + 768) = d3v;
    }
    __syncthreads();
    {   // float4 combine + writes: o4 = mt*256 + r*64 + qc, cch stride 512 (f4)
        float4* b4 = (float4*)buf;
        int o4 = t;
        int mt2 = o4 >> 8, r2 = (o4 >> 6) & 3, qc2 = o4 & 63;
        float4 s0 = b4[o4], s1 = b4[512 + o4], s2 = b4[1024 + o4], s3 = b4[1536 + o4];
        float4 sv;
        sv.x = (s0.x + s1.x) + (s2.x + s3.x);
        sv.y = (s0.y + s1.y) + (s2.y + s3.y);
        sv.z = (s0.z + s1.z) + (s2.z + s3.z);
        sv.w = (s0.w + s1.w) + (s2.w + s3.w);
        if (mt2 == 0) {
            float sc = sinv[r2];
            sv.x *= sc; sv.y *= sc; sv.z *= sc; sv.w *= sc;
            *(float4*)(M2 + base + (size_t)(i0 + r2) * Cc + 4*qc2) = sv;
        } else {
            float4 fb = *(const float4*)(fa_aff_b + 4*qc2);
            sv.x += fb.x; sv.y += fb.y; sv.z += fb.z; sv.w += fb.w;
            *(float4*)(lf2 + base + (size_t)(i0 + r2) * Cc + 4*qc2) = sv;
        }
    }
}

// ---------------- dispatch 3: feat_aggr rows (512 thr, 4 rows), vectorized ----------------
__global__ void k_row2f(const float* __restrict__ nfT2, const float* __restrict__ M2,
                        const float* __restrict__ lf2, const float* __restrict__ g,
                        const float* __restrict__ bb, float* __restrict__ x2,
                        float* __restrict__ nf3) {
    __shared__ __align__(16) float smT[Cc*4];
    __shared__ __align__(16) float saraw[4*NN];
    __shared__ __align__(16) float saT[NN*4];
    __shared__ __align__(16) float buf[8192];
    __shared__ float sh[16];
    int t = threadIdx.x, h = t >> 8, tt = t & 255;
    int b = blockIdx.x & 7;
    int i0 = (blockIdx.x >> 3) * 4;
    size_t base = (size_t)b * NN * Cc;
    {
        const float* src = M2 + base + (size_t)i0 * Cc;
        #pragma unroll
        for (int o = t; o < 1024; o += 512) {
            int c = o >> 2, r = o & 3;
            smT[o] = src[(size_t)r * Cc + c];
        }
    }
    __syncthreads();
    // phase A
    {
        int q = t & 63, cid = t >> 6;
        if (q < 50) {
            int c0 = cid * 32;
            const float* nfp = nfT2 + (size_t)b * Cc * JP + (size_t)c0 * JP + 4*q;
            float4 z4 = make_float4(0.f,0.f,0.f,0.f);
            float4 a0 = z4, a1 = z4, a2 = z4, a3 = z4;
            #pragma unroll 8
            for (int c = 0; c < 32; c++) {
                float4 v  = *(const float4*)(nfp + (size_t)c * JP);
                float4 mv = *(const float4*)(&smT[(c0 + c) * 4]);
                FMA4(a0, mv.x, v); FMA4(a1, mv.y, v);
                FMA4(a2, mv.z, v); FMA4(a3, mv.w, v);
            }
            float* pp = buf + cid * 800 + 4*q;
            *(float4*)(pp      ) = a0;
            *(float4*)(pp + 200) = a1;
            *(float4*)(pp + 400) = a2;
            *(float4*)(pp + 600) = a3;
        }
    }
    __syncthreads();
    for (int o = t; o < 800; o += 512) {
        float s = 0.f;
        #pragma unroll
        for (int p = 0; p < 8; p++) s += buf[p*800 + o];
        saraw[o] = s;
    }
    __syncthreads();
    // softmax rows (h, h+2)
    int lr0 = h, lr1 = h + 2;
    float2 vm;
    vm.x = (tt < NN) ? saraw[lr0*NN + tt] : -INFINITY;
    vm.y = (tt < NN) ? saraw[lr1*NN + tt] : -INFINITY;
    float2 m = half_reduce_max2(vm, sh, h);
    float e0 = (tt < NN) ? expf(SCALE * (vm.x - m.x)) : 0.f;
    float e1 = (tt < NN) ? expf(SCALE * (vm.y - m.y)) : 0.f;
    float2 sum = half_reduce_sum2(make_float2(e0, e1), sh, h);
    if (tt < NN) { saT[tt*4 + lr0] = e0 / sum.x; saT[tt*4 + lr1] = e1 / sum.y; }
    __syncthreads();
    // phase C: y = A @ lf2
    const float* l2b = lf2 + base;
    {
        int qc = t & 63, jc = t >> 6;
        int j0 = jc * 25;
        float4 z4 = make_float4(0.f,0.f,0.f,0.f);
        float4 u0 = z4, u1 = z4, u2 = z4, u3 = z4;
        #pragma unroll 5
        for (int j = j0; j < j0 + 25; j++) {
            float4 pv = *(const float4*)(l2b + (size_t)j * Cc + 4*qc);
            float4 av = *(const float4*)(&saT[j*4]);
            FMA4(u0, av.x, pv); FMA4(u1, av.y, pv);
            FMA4(u2, av.z, pv); FMA4(u3, av.w, pv);
        }
        float* pp = buf + jc*1024 + 4*qc;
        *(float4*)(pp      ) = u0;
        *(float4*)(pp + 256) = u1;
        *(float4*)(pp + 512) = u2;
        *(float4*)(pp + 768) = u3;
    }
    __syncthreads();
    float y0 = 0.f, y1 = 0.f;
    #pragma unroll
    for (int p = 0; p < 8; p++) { y0 += buf[p*1024 + t]; y1 += buf[p*1024 + t + 512]; }
    // LN + leaky + l2norm epilogue
    float gg = g[tt], bbv = bb[tt];
    float2 mean2 = half_reduce_sum2(make_float2(y0, y1), sh, h);
    float d0 = y0 - mean2.x * (1.f/256.f);
    float d1 = y1 - mean2.y * (1.f/256.f);
    float2 var2 = half_reduce_sum2(make_float2(d0*d0, d1*d1), sh, h);
    float z0 = d0 / sqrtf(var2.x * (1.f/256.f) + LN_EPS) * gg + bbv;
    float z1 = d1 / sqrtf(var2.y * (1.f/256.f) + LN_EPS) * gg + bbv;
    z0 = (z0 >= 0.f) ? z0 : SLOPE * z0;
    z1 = (z1 >= 0.f) ? z1 : SLOPE * z1;
    x2[base + (size_t)(i0 + lr0) * Cc + tt] = z0;
    x2[base + (size_t)(i0 + lr1) * Cc + tt] = z1;
    float2 ss2 = half_reduce_sum2(make_float2(z0*z0, z1*z1), sh, h);
    nf3[base + (size_t)(i0 + lr0) * Cc + tt] = z0 / fmaxf(sqrtf(ss2.x), N_EPS);
    nf3[base + (size_t)(i0 + lr1) * Cc + tt] = z1 / fmaxf(sqrtf(ss2.y), N_EPS);
}

// ---------------- dispatch 4: fused wsum + node_att (4 rows/block, 256 thr) ----------------
__global__ void k_natt(const float* __restrict__ x2, const float* __restrict__ nf3,
                       const float* __restrict__ pos, const float* __restrict__ w,
                       const float* __restrict__ nb, float* __restrict__ out) {
    __shared__ float svb[4][Cc];
    int t = threadIdx.x, lane = t & 63, wv = t >> 6;
    int b = blockIdx.x & 7;
    int i = (blockIdx.x >> 3) * 4 + wv;
    const float4* slab = (const float4*)(nf3 + (size_t)b * NN * Cc);
    float4 acc = make_float4(0.f, 0.f, 0.f, 0.f);
    for (int j = wv * 50; j < wv * 50 + 50; j++) {
        float4 q = slab[j * 64 + lane];
        float wj = w[j];
        acc.x = fmaf(wj, q.x, acc.x);
        acc.y = fmaf(wj, q.y, acc.y);
        acc.z = fmaf(wj, q.z, acc.z);
        acc.w = fmaf(wj, q.w, acc.w);
    }
    ((float4*)&svb[wv][0])[lane] = acc;
    __syncthreads();
    float4 p0 = ((const float4*)&svb[0][0])[lane];
    float4 p1 = ((const float4*)&svb[1][0])[lane];
    float4 p2 = ((const float4*)&svb[2][0])[lane];
    float4 p3 = ((const float4*)&svb[3][0])[lane];
    float4 vb;
    vb.x = (p0.x + p1.x) + (p2.x + p3.x);
    vb.y = (p0.y + p1.y) + (p2.y + p3.y);
    vb.z = (p0.z + p1.z) + (p2.z + p3.z);
    vb.w = (p0.w + p1.w) + (p2.w + p3.w);
    size_t bi = (size_t)b * NN + i;
    float4 nv = ((const float4*)(nf3 + bi * Cc))[lane];
    float val = nv.x*vb.x + nv.y*vb.y + nv.z*vb.z + nv.w*vb.w;
    if (lane < 9) val += pos[bi * 9 + lane] * w[NN + lane];
    val = wave_reduce_sum(val);
    float att = 1.f / (1.f + expf(-(val + nb[0])));
    float4 xo = ((const float4*)(x2 + bi * Cc))[lane];
    xo.x *= att; xo.y *= att; xo.z *= att; xo.w *= att;
    ((float4*)(out + bi * Cc))[lane] = xo;
}

// ---------------- launcher ----------------
extern "C" void kernel_launch(void* const* d_in, const int* in_sizes, int n_in,
                              void* d_out, int out_size, void* d_ws, size_t ws_size,
                              hipStream_t stream) {
    (void)in_sizes; (void)n_in; (void)out_size; (void)ws_size;
    const float* lf       = (const float*)d_in[0];
    const float* pos      = (const float*)d_in[2];
    const float* dp_adj_w = (const float*)d_in[3];
    const float* dp_aff_w = (const float*)d_in[4];
    const float* dp_aff_b = (const float*)d_in[5];
    const float* dp_ln_g  = (const float*)d_in[6];
    const float* dp_ln_b  = (const float*)d_in[7];
    const float* fa_adj_w = (const float*)d_in[8];
    const float* fa_aff_w = (const float*)d_in[9];
    const float* fa_aff_b = (const float*)d_in[10];
    const float* fa_ln_g  = (const float*)d_in[11];
    const float* fa_ln_b  = (const float*)d_in[12];
    const float* na_w     = (const float*)d_in[13];
    const float* na_b     = (const float*)d_in[14];
    float* out = (float*)d_out;
    float* ws  = (float*)d_ws;

    float* nfT  = ws;                    // Bn*Cc*JP
    float* nfT2 = nfT  + Bn * Cc * JP;   // Bn*Cc*JP
    float* M    = nfT2 + Bn * Cc * JP;   // RR*Cc  (M2 written in-place)
    float* P    = M    + RR * Cc;        // RR*Cc
    float* lf2  = P    + RR * Cc;        // RR*Cc
    float* x2   = lf2  + RR * Cc;        // RR*Cc
    float* nf3  = x2   + RR * Cc;        // RR*Cc
    float* WT1  = nf3  + RR * Cc;        // Cc*Cc
    float* WT2  = WT1  + Cc * Cc;        // Cc*Cc

    k_tr   <<<128,        dim3(256), 0, stream>>>(dp_aff_w, fa_aff_w, WT1, WT2);
    k_pre  <<<RR/8 * 2,   dim3(256), 0, stream>>>(lf, dp_adj_w, WT1, nfT, M, P);
    k_row1f<<<Bn * NN/4,  dim3(512), 0, stream>>>(nfT, M, P, dp_aff_b, dp_ln_g, dp_ln_b,
                                                  fa_adj_w, WT2, fa_aff_b, nfT2, M, lf2);
    k_row2f<<<Bn * NN/4,  dim3(512), 0, stream>>>(nfT2, M, lf2, fa_ln_g, fa_ln_b, x2, nf3);
    k_natt <<<Bn * NN/4,  dim3(256), 0, stream>>>(x2, nf3, pos, na_w, na_b, out);
}